// Round 4
// baseline (347.487 us; speedup 1.0000x reference)
//
#include <hip/hip_runtime.h>
#include <math.h>

using bf16x8 = __attribute__((ext_vector_type(8))) short;
using f32x4  = __attribute__((ext_vector_type(4))) float;

// ---- bf16 helpers ----
__device__ __forceinline__ unsigned short f2bf(float v) {          // RNE pack
  unsigned int b = __float_as_uint(v);
  unsigned int r = (b + 0x7fffu + ((b >> 16) & 1u)) >> 16;
  return (unsigned short)r;
}
__device__ __forceinline__ float bf2f(unsigned short u) {
  return __uint_as_float(((unsigned int)u) << 16);
}

// ============================ mega0: pack (blocks 0..37) || hist (blocks 38..) (proven R16) ============================

__global__ void mega0_kernel(const float* __restrict__ W0f, unsigned short* __restrict__ Bp0,
                             const float* __restrict__ W1f, unsigned short* __restrict__ Bp1,
                             const int* __restrict__ dst, int* __restrict__ deg, int E) {
  int bx = blockIdx.x;
  if (bx >= 38) {                                // ---- hist ----
    int t = (bx - 38) * 256 + threadIdx.x;
    if (t < E) atomicAdd(&deg[dst[t]], 1);
    return;
  }
  int idx = bx * 256 + threadIdx.x;
  if (idx < 8192) {
    int lane = idx & 63, s = (idx >> 6) & 7, t = idx >> 9;
    int n = t * 16 + (lane & 15), quad = lane >> 4;
    unsigned short* o = Bp0 + (size_t)idx * 8;
    #pragma unroll
    for (int j = 0; j < 8; ++j) {
      int k = s * 32 + quad * 8 + j;
      o[j] = f2bf(W0f[(size_t)k * 256 + n]);
    }
  } else if (idx < 8192 + 1536) {
    int i1 = idx - 8192;
    int lane = i1 & 63, s = (i1 >> 6) & 7, t = i1 >> 9;
    int n = t * 16 + (lane & 15), quad = lane >> 4;
    unsigned short* o = Bp1 + (size_t)i1 * 8;
    #pragma unroll
    for (int j = 0; j < 8; ++j) {
      int k = s * 32 + quad * 8 + j;
      o[j] = (n < 40) ? f2bf(W1f[(size_t)k * 40 + n]) : 0;
    }
  }
}

// ============================ 3-phase parallel scan (proven R5-R16) ============================

__global__ void block_sum_kernel(const int* __restrict__ deg, int* __restrict__ bsum, int n) {
  __shared__ int red[4];
  int t = threadIdx.x, i = blockIdx.x * 256 + t;
  int v = (i < n) ? deg[i] : 0;
  #pragma unroll
  for (int off = 32; off; off >>= 1) v += __shfl_xor(v, off);
  if ((t & 63) == 0) red[t >> 6] = v;
  __syncthreads();
  if (t == 0) bsum[blockIdx.x] = red[0] + red[1] + red[2] + red[3];
}

__global__ void scan_bsum_kernel(const int* __restrict__ bsum, int* __restrict__ boffs,
                                 int* __restrict__ offsets, int nb, int n) {
  __shared__ int tmp[1024];
  int t = threadIdx.x;
  int v = (t < nb) ? bsum[t] : 0;
  tmp[t] = v;
  __syncthreads();
  #pragma unroll
  for (int off = 1; off < 1024; off <<= 1) {
    int add = (t >= off) ? tmp[t - off] : 0;
    __syncthreads();
    tmp[t] += add;
    __syncthreads();
  }
  if (t < nb) boffs[t] = tmp[t] - v;
  if (t == 1023) offsets[n] = tmp[1023];
}

__global__ void write_offsets_kernel(const int* __restrict__ deg, const int* __restrict__ boffs,
                                     int* __restrict__ offsets, int* __restrict__ cursor, int n) {
  __shared__ int tmp[256];
  int t = threadIdx.x, i = blockIdx.x * 256 + t;
  int v = (i < n) ? deg[i] : 0;
  tmp[t] = v;
  __syncthreads();
  #pragma unroll
  for (int off = 1; off < 256; off <<= 1) {
    int add = (t >= off) ? tmp[t - off] : 0;
    __syncthreads();
    tmp[t] += add;
    __syncthreads();
  }
  if (i < n) {
    int o = boffs[blockIdx.x] + tmp[t] - v;
    offsets[i] = o;
    cursor[i] = o;
  }
}

// ============================ gemm0: R0 geometry, csr branch removed ============================
// 256 rows x 128-col half per block, 8 waves (4 row x 2 col), 64 KB LDS, 2 blocks/CU,
// VGPR+AGPR = 64+64 = 128 exactly (16 waves/CU). Proven-72us structure, now measured alone.

__global__ __launch_bounds__(512) void gemm0_kernel(
    const float* __restrict__ A, const unsigned short* __restrict__ Bp,
    unsigned short* __restrict__ Zb,
    const float* __restrict__ al, const float* __restrict__ arr,
    float* __restrict__ el, float* __restrict__ er, int M) {
  __shared__ unsigned short Bs[32768];           // 64 KB: this col-half of packed W0
  int bx = blockIdx.x;
  int tid = threadIdx.x;

  int gx = bx >> 1, y = bx & 1;
  int wid = tid >> 6, lane = tid & 63;
  int quad = lane >> 4, col16 = lane & 15;
  int wr = wid >> 1, wc = wid & 1;               // 4 row-waves x 2 col-waves
  int rowbase = gx * 256 + wr * 64;

  // clamped row pointers (branch-free A loads; clamped rows only affect unwritten C-rows)
  const float* aptr[4];
  #pragma unroll
  for (int rt = 0; rt < 4; ++rt) {
    int m = rowbase + rt * 16 + col16;
    if (m > M - 1) m = M - 1;
    aptr[rt] = A + (size_t)m * 256 + quad * 8;
  }

  auto loadA = [&](bf16x8* fr, int s) {
    #pragma unroll
    for (int rt = 0; rt < 4; ++rt) {
      const float* ap = aptr[rt] + s * 32;
      float4 a0 = *(const float4*)ap;
      float4 a1 = *(const float4*)(ap + 4);
      fr[rt][0] = (short)f2bf(a0.x); fr[rt][1] = (short)f2bf(a0.y);
      fr[rt][2] = (short)f2bf(a0.z); fr[rt][3] = (short)f2bf(a0.w);
      fr[rt][4] = (short)f2bf(a1.x); fr[rt][5] = (short)f2bf(a1.y);
      fr[rt][6] = (short)f2bf(a1.z); fr[rt][7] = (short)f2bf(a1.w);
    }
  };

  // issue first k-step A loads before staging: latency overlaps the 64 KB copy + barrier
  bf16x8 afc[4];
  loadA(afc, 0);

  {                                              // stage 64 KB = 4096 int4, 512 thr x 8
    const int4* s4 = (const int4*)(Bp + (size_t)y * 32768);
    int4* d4 = (int4*)Bs;
    #pragma unroll
    for (int i = 0; i < 8; ++i) d4[tid + i * 512] = s4[tid + i * 512];
  }
  __syncthreads();

  f32x4 acc[4][4];
  #pragma unroll
  for (int rt = 0; rt < 4; ++rt)
    #pragma unroll
    for (int ct = 0; ct < 4; ++ct) acc[rt][ct] = {0.f, 0.f, 0.f, 0.f};

  const bf16x8* BsV = (const bf16x8*)Bs;

  #pragma unroll
  for (int s = 0; s < 8; ++s) {
    bf16x8 afn[4];
    if (s < 7) loadA(afn, s + 1);                // prefetch next k-step
    #pragma unroll
    for (int ct = 0; ct < 4; ++ct) {
      bf16x8 bf = BsV[((wc * 4 + ct) * 8 + s) * 64 + lane];
      #pragma unroll
      for (int rt = 0; rt < 4; ++rt)
        acc[rt][ct] = __builtin_amdgcn_mfma_f32_16x16x32_bf16(afc[rt], bf, acc[rt][ct], 0, 0, 0);
    }
    if (s < 7) {
      #pragma unroll
      for (int rt = 0; rt < 4; ++rt) afc[rt] = afn[rt];
    }
  }

  int hw = y * 2 + wc;
  float al_c[4], ar_c[4];
  #pragma unroll
  for (int ct = 0; ct < 4; ++ct) {
    int col = y * 128 + (wc * 4 + ct) * 16 + col16;
    al_c[ct] = al[col];
    ar_c[ct] = arr[col];
  }

  #pragma unroll
  for (int rt = 0; rt < 4; ++rt) {
    int row0 = rowbase + rt * 16 + quad * 4;
    #pragma unroll
    for (int r = 0; r < 4; ++r) {
      int row = row0 + r;
      if (row < M) {
        #pragma unroll
        for (int ct = 0; ct < 4; ++ct) {
          int col = y * 128 + (wc * 4 + ct) * 16 + col16;
          Zb[(size_t)row * 256 + col] = f2bf(acc[rt][ct][r]);
        }
      }
      float pe = 0.f, pr = 0.f;
      #pragma unroll
      for (int ct = 0; ct < 4; ++ct) {
        float zv = acc[rt][ct][r];
        pe += zv * al_c[ct];
        pr += zv * ar_c[ct];
      }
      pe += __shfl_xor(pe, 1); pr += __shfl_xor(pr, 1);
      pe += __shfl_xor(pe, 2); pr += __shfl_xor(pr, 2);
      pe += __shfl_xor(pe, 4); pr += __shfl_xor(pr, 4);
      pe += __shfl_xor(pe, 8); pr += __shfl_xor(pr, 8);
      if (col16 == 0 && row < M) {
        el[(size_t)row * 4 + hw] = pe;
        er[(size_t)row * 4 + hw] = pr;
      }
    }
  }
}

// ============================ csr scatter: standalone, no LDS, 1 edge/thread ============================
// 32 waves/CU (no LDS, tiny regs) -> 2x the atomic-latency-hiding residency the fused
// version had; one independent {load dst, atomicAdd, store} chain per thread.

__global__ __launch_bounds__(256) void csr_kernel(
    const int* __restrict__ src, const int* __restrict__ dst,
    int* __restrict__ cursor, int* __restrict__ ssrc, int E) {
  int e = blockIdx.x * 256 + threadIdx.x;
  if (e < E) {
    int p = atomicAdd(&cursor[dst[e]], 1);
    ssrc[p] = src[e];
  }
}

// ============================ layer-1 GEMM (proven R9) ============================

__global__ __launch_bounds__(256) void gemm1_mfma_kernel(
    const unsigned short* __restrict__ Ab, const unsigned short* __restrict__ Bp,
    unsigned short* __restrict__ Zb,
    const float* __restrict__ al, const float* __restrict__ arr,
    float* __restrict__ el, float* __restrict__ er, int M) {
  int wid = threadIdx.x >> 6, lane = threadIdx.x & 63;
  int quad = lane >> 4, col16 = lane & 15;
  int m = blockIdx.x * 64 + wid * 16 + col16;

  f32x4 acc[3];
  #pragma unroll
  for (int t = 0; t < 3; ++t) acc[t] = {0.f, 0.f, 0.f, 0.f};

  const bf16x8* BpV = (const bf16x8*)Bp;

  for (int s = 0; s < 8; ++s) {
    bf16x8 af;
    if (m < M) {
      af = *(const bf16x8*)(Ab + (size_t)m * 256 + s * 32 + quad * 8);
    } else {
      #pragma unroll
      for (int j = 0; j < 8; ++j) af[j] = 0;
    }
    #pragma unroll
    for (int t = 0; t < 3; ++t) {
      bf16x8 bf = BpV[(t * 8 + s) * 64 + lane];
      acc[t] = __builtin_amdgcn_mfma_f32_16x16x32_bf16(af, bf, acc[t], 0, 0, 0);
    }
  }

  float al_c[3], ar_c[3];
  #pragma unroll
  for (int t = 0; t < 3; ++t) {
    int col = t * 16 + col16;
    al_c[t] = (col < 40) ? al[col] : 0.f;
    ar_c[t] = (col < 40) ? arr[col] : 0.f;
  }

  int row0 = blockIdx.x * 64 + wid * 16 + quad * 4;
  #pragma unroll
  for (int r = 0; r < 4; ++r) {
    int row = row0 + r;
    if (row < M) {
      #pragma unroll
      for (int t = 0; t < 3; ++t) {
        int col = t * 16 + col16;
        if (col < 40) Zb[(size_t)row * 40 + col] = f2bf(acc[t][r]);
      }
    }
    float pe = 0.f, pr = 0.f;
    #pragma unroll
    for (int t = 0; t < 3; ++t) {
      pe += acc[t][r] * al_c[t];
      pr += acc[t][r] * ar_c[t];
    }
    pe += __shfl_xor(pe, 1); pr += __shfl_xor(pr, 1);
    pe += __shfl_xor(pe, 2); pr += __shfl_xor(pr, 2);
    pe += __shfl_xor(pe, 4); pr += __shfl_xor(pr, 4);
    pe += __shfl_xor(pe, 8); pr += __shfl_xor(pr, 8);
    if (col16 == 0 && row < M) {
      el[row] = pe;
      er[row] = pr;
    }
  }
}

// ============================ layer-0 aggregation (proven R12) ============================

__global__ __launch_bounds__(256) void agg0_kernel(
    const int* __restrict__ offs, const int* __restrict__ ssrc,
    const float* __restrict__ el, const float* __restrict__ er,
    const unsigned short* __restrict__ zb, const float* __restrict__ bias,
    unsigned short* __restrict__ outb, int n) {
  __shared__ float sW[4][16][4];
  __shared__ int   sS[4][16];
  int wid  = threadIdx.x >> 6;
  int lane = threadIdx.x & 63;
  int node = blockIdx.x * 4 + wid;
  if (node >= n) return;
  int c = lane & 3, eoff = lane >> 2;
  int half = lane >> 5, colg = lane & 31, h2 = colg >> 3;
  int s0 = offs[node], s1 = offs[node + 1];
  float er_c = er[node * 4 + c];

  float ssum = 0.f;
  float acc[8] = {0.f, 0.f, 0.f, 0.f, 0.f, 0.f, 0.f, 0.f};
  for (int base = s0; base < s1; base += 16) {
    int cnt = min(16, s1 - base);
    if (eoff < cnt) {
      int esrc = ssrc[base + eoff];
      float v = el[esrc * 4 + c] + er_c;
      v = v > 0.f ? v : 0.2f * v;              // leaky_relu(0.2)
      sW[wid][eoff][c] = expf(v);              // no max-shift (scores O(+-10))
      if (c == 0) sS[wid][eoff] = esrc;
    }
    for (int j = 0; j < cnt; j += 2) {
      int jj = j + half;
      float w = (jj < cnt) ? sW[wid][jj][h2] : 0.f;
      int sn = sS[wid][(jj < cnt) ? jj : (cnt - 1)];
      ssum += w;
      bf16x8 zu = *(const bf16x8*)(zb + (size_t)sn * 256 + (colg << 3));
      #pragma unroll
      for (int i = 0; i < 8; ++i)
        acc[i] += w * bf2f((unsigned short)zu[i]);
    }
  }

  ssum += __shfl_xor(ssum, 32);
  #pragma unroll
  for (int i = 0; i < 8; ++i) acc[i] += __shfl_xor(acc[i], 32);

  float inv = (s1 > s0) ? 1.f / ssum : 0.f;    // deg==0 -> out = bias
  if (half == 0) {
    const float4 b0v = *(const float4*)(bias + (colg << 3));
    const float4 b1v = *(const float4*)(bias + (colg << 3) + 4);
    float bb[8] = {b0v.x, b0v.y, b0v.z, b0v.w, b1v.x, b1v.y, b1v.z, b1v.w};
    bf16x8 u;
    #pragma unroll
    for (int i = 0; i < 8; ++i) {
      float o = acc[i] * inv + bb[i];
      o = o > 0.f ? o : expm1f(o);             // ELU
      u[i] = (short)f2bf(o);
    }
    *(bf16x8*)(outb + (size_t)node * 256 + (colg << 3)) = u;
  }
}

// ============================ layer-1 aggregation (proven R12) ============================

__global__ __launch_bounds__(256) void agg1_kernel(
    const int* __restrict__ offs, const int* __restrict__ ssrc,
    const float* __restrict__ el, const float* __restrict__ er,
    const unsigned short* __restrict__ zb, const float* __restrict__ bias,
    float* __restrict__ out, int n) {
  __shared__ float sW[4][64];
  __shared__ int   sS[4][64];
  int wid  = threadIdx.x >> 6;
  int lane = threadIdx.x & 63;
  int node = blockIdx.x * 4 + wid;
  if (node >= n) return;
  int half = lane >> 5, d = lane & 31;
  int s0 = offs[node], s1 = offs[node + 1];
  float ern = er[node];

  float ssum = 0.f;
  float2 acc = make_float2(0.f, 0.f);
  for (int base = s0; base < s1; base += 64) {
    int cnt = min(64, s1 - base);
    if (lane < cnt) {
      int esrc = ssrc[base + lane];
      float v = el[esrc] + ern;
      v = v > 0.f ? v : 0.2f * v;
      sW[wid][lane] = expf(v);                 // no max-shift
      sS[wid][lane] = esrc;
    }
    for (int j = 0; j < cnt; j += 2) {
      int jj = j + half;
      float w = (jj < cnt) ? sW[wid][jj] : 0.f;
      int sn = sS[wid][(jj < cnt) ? jj : (cnt - 1)];
      ssum += w;
      if (d < 20) {
        unsigned zp = *(const unsigned*)(zb + (size_t)sn * 40 + (d << 1));
        acc.x += w * bf2f((unsigned short)(zp & 0xffffu));
        acc.y += w * bf2f((unsigned short)(zp >> 16));
      }
    }
  }

  ssum  += __shfl_xor(ssum, 32);
  acc.x += __shfl_xor(acc.x, 32);
  acc.y += __shfl_xor(acc.y, 32);

  float inv = (s1 > s0) ? 1.f / ssum : 0.f;
  if (half == 0 && d < 20) {
    float2 o;
    o.x = acc.x * inv + bias[(d << 1) + 0];
    o.y = acc.y * inv + bias[(d << 1) + 1];
    *(float2*)(out + (size_t)node * 40 + (d << 1)) = o;
  }
}

// ============================ launch ============================

extern "C" void kernel_launch(void* const* d_in, const int* in_sizes, int n_in,
                              void* d_out, int out_size, void* d_ws, size_t ws_size,
                              hipStream_t stream) {
  const float* x   = (const float*)d_in[0];
  const int*   src = (const int*)d_in[1];
  const int*   dst = (const int*)d_in[2];
  const float* W0  = (const float*)d_in[3];
  const float* al0 = (const float*)d_in[4];
  const float* ar0 = (const float*)d_in[5];
  const float* b0  = (const float*)d_in[6];
  const float* W1  = (const float*)d_in[7];
  const float* al1 = (const float*)d_in[8];
  const float* ar1 = (const float*)d_in[9];
  const float* b1  = (const float*)d_in[10];
  float* out = (float*)d_out;

  const int N = in_sizes[0] / 256;   // 50000
  const int E = in_sizes[1];         // 800000
  const int NB = (N + 255) / 256;    // 196 scan blocks

  char* ws = (char*)d_ws;
  size_t off = 0;
  auto alloc = [&](size_t bytes) {
    void* p = ws + off;
    off = (off + bytes + 255) & ~(size_t)255;
    return p;
  };
  unsigned short* z0b = (unsigned short*)alloc((size_t)N * 256 * 2);
  unsigned short* h0b = (unsigned short*)alloc((size_t)N * 256 * 2);
  unsigned short* z1b = (unsigned short*)alloc((size_t)N * 40 * 2);
  unsigned short* w0p = (unsigned short*)alloc((size_t)16 * 8 * 64 * 8 * 2);
  unsigned short* w1p = (unsigned short*)alloc((size_t)3 * 8 * 64 * 8 * 2);
  float* el0  = (float*)alloc((size_t)N * 4 * 4);
  float* er0  = (float*)alloc((size_t)N * 4 * 4);
  float* el1  = (float*)alloc((size_t)N * 4);
  float* er1  = (float*)alloc((size_t)N * 4);
  int* deg    = (int*)alloc((size_t)N * 4);
  int* offs   = (int*)alloc((size_t)(N + 1) * 4);
  int* cursor = (int*)alloc((size_t)N * 4);
  int* bsum   = (int*)alloc((size_t)NB * 4);
  int* boffs  = (int*)alloc((size_t)NB * 4);
  int* ssrc   = (int*)alloc((size_t)E * 4);
  (void)off; (void)ws_size; (void)n_in; (void)out_size;

  const int nG = ((N + 255) / 256) * 2;          // 392 gemm0 blocks (256 rows x col-half)
  const int nH = (E + 255) / 256;                // 3125 hist blocks

  // 1. deg = 0
  hipMemsetAsync(deg, 0, (size_t)N * 4, stream);
  // 2. pack || hist (no LDS -> full occupancy)
  mega0_kernel<<<38 + nH, 256, 0, stream>>>(W0, w0p, W1, w1p, dst, deg, E);
  // 3-5. exclusive scan, 3-phase
  block_sum_kernel<<<NB, 256, 0, stream>>>(deg, bsum, N);
  scan_bsum_kernel<<<1, 1024, 0, stream>>>(bsum, boffs, offs, NB, N);
  write_offsets_kernel<<<NB, 256, 0, stream>>>(deg, boffs, offs, cursor, N);
  // 6a. gemm0 alone (clean counters; R0-proven geometry)
  gemm0_kernel<<<nG, 512, 0, stream>>>(x, w0p, z0b, al0, ar0, el0, er0, N);
  // 6b. csr scatter alone (no LDS -> 32 waves/CU of atomic TLP)
  csr_kernel<<<nH, 256, 0, stream>>>(src, dst, cursor, ssrc, E);
  // 7. layer-0 aggregation + ELU -> h0b
  agg0_kernel<<<(N + 3) / 4, 256, 0, stream>>>(offs, ssrc, el0, er0, z0b, b0, h0b, N);
  // 8. layer-1 GEMM + fused el/er
  gemm1_mfma_kernel<<<(N + 63) / 64, 256, 0, stream>>>(h0b, w1p, z1b, al1, ar1, el1, er1, N);
  // 9. layer-1 aggregation -> out
  agg1_kernel<<<(N + 3) / 4, 256, 0, stream>>>(offs, ssrc, el1, er1, z1b, b1, out, N);
}

// Round 6
// 318.082 us; speedup vs baseline: 1.0924x; 1.0924x over previous
//
#include <hip/hip_runtime.h>
#include <math.h>

using bf16x8 = __attribute__((ext_vector_type(8))) short;
using f32x4  = __attribute__((ext_vector_type(4))) float;

// ---- bf16 helpers ----
__device__ __forceinline__ unsigned short f2bf(float v) {          // RNE pack
  unsigned int b = __float_as_uint(v);
  unsigned int r = (b + 0x7fffu + ((b >> 16) & 1u)) >> 16;
  return (unsigned short)r;
}
__device__ __forceinline__ float bf2f(unsigned short u) {
  return __uint_as_float(((unsigned int)u) << 16);
}

// ============================ mega0: pack (blocks 0..37) || hist (blocks 38..) (proven R16) ============================

__global__ void mega0_kernel(const float* __restrict__ W0f, unsigned short* __restrict__ Bp0,
                             const float* __restrict__ W1f, unsigned short* __restrict__ Bp1,
                             const int* __restrict__ dst, int* __restrict__ deg, int E) {
  int bx = blockIdx.x;
  if (bx >= 38) {                                // ---- hist ----
    int t = (bx - 38) * 256 + threadIdx.x;
    if (t < E) atomicAdd(&deg[dst[t]], 1);
    return;
  }
  int idx = bx * 256 + threadIdx.x;
  if (idx < 8192) {
    int lane = idx & 63, s = (idx >> 6) & 7, t = idx >> 9;
    int n = t * 16 + (lane & 15), quad = lane >> 4;
    unsigned short* o = Bp0 + (size_t)idx * 8;
    #pragma unroll
    for (int j = 0; j < 8; ++j) {
      int k = s * 32 + quad * 8 + j;
      o[j] = f2bf(W0f[(size_t)k * 256 + n]);
    }
  } else if (idx < 8192 + 1536) {
    int i1 = idx - 8192;
    int lane = i1 & 63, s = (i1 >> 6) & 7, t = i1 >> 9;
    int n = t * 16 + (lane & 15), quad = lane >> 4;
    unsigned short* o = Bp1 + (size_t)i1 * 8;
    #pragma unroll
    for (int j = 0; j < 8; ++j) {
      int k = s * 32 + quad * 8 + j;
      o[j] = (n < 40) ? f2bf(W1f[(size_t)k * 40 + n]) : 0;
    }
  }
}

// ============================ 3-phase parallel scan (proven R5-R16) ============================

__global__ void block_sum_kernel(const int* __restrict__ deg, int* __restrict__ bsum, int n) {
  __shared__ int red[4];
  int t = threadIdx.x, i = blockIdx.x * 256 + t;
  int v = (i < n) ? deg[i] : 0;
  #pragma unroll
  for (int off = 32; off; off >>= 1) v += __shfl_xor(v, off);
  if ((t & 63) == 0) red[t >> 6] = v;
  __syncthreads();
  if (t == 0) bsum[blockIdx.x] = red[0] + red[1] + red[2] + red[3];
}

__global__ void scan_bsum_kernel(const int* __restrict__ bsum, int* __restrict__ boffs,
                                 int* __restrict__ offsets, int nb, int n) {
  __shared__ int tmp[1024];
  int t = threadIdx.x;
  int v = (t < nb) ? bsum[t] : 0;
  tmp[t] = v;
  __syncthreads();
  #pragma unroll
  for (int off = 1; off < 1024; off <<= 1) {
    int add = (t >= off) ? tmp[t - off] : 0;
    __syncthreads();
    tmp[t] += add;
    __syncthreads();
  }
  if (t < nb) boffs[t] = tmp[t] - v;
  if (t == 1023) offsets[n] = tmp[1023];
}

__global__ void write_offsets_kernel(const int* __restrict__ deg, const int* __restrict__ boffs,
                                     int* __restrict__ offsets, int* __restrict__ cursor, int n) {
  __shared__ int tmp[256];
  int t = threadIdx.x, i = blockIdx.x * 256 + t;
  int v = (i < n) ? deg[i] : 0;
  tmp[t] = v;
  __syncthreads();
  #pragma unroll
  for (int off = 1; off < 256; off <<= 1) {
    int add = (t >= off) ? tmp[t - off] : 0;
    __syncthreads();
    tmp[t] += add;
    __syncthreads();
  }
  if (i < n) {
    int o = boffs[blockIdx.x] + tmp[t] - v;
    offsets[i] = o;
    cursor[i] = o;
  }
}

// ============================ mega2: EXACT R0 fused gemm0 || csr (proven 72us) ============================

__global__ __launch_bounds__(512) void mega2_kernel(
    const float* __restrict__ A, const unsigned short* __restrict__ Bp,
    unsigned short* __restrict__ Zb,
    const float* __restrict__ al, const float* __restrict__ arr,
    float* __restrict__ el, float* __restrict__ er, int M,
    const int* __restrict__ src, const int* __restrict__ dst,
    int* __restrict__ cursor, int* __restrict__ ssrc, int E, int nG, int nC) {
  __shared__ unsigned short Bs[32768];           // 64 KB: this col-half of packed W0
  int bx = blockIdx.x;
  int tid = threadIdx.x;

  if (bx >= nG) {                                // ---- build_csr part ----
    int stride = nC * 512;
    for (int e = (bx - nG) * 512 + tid; e < E; e += stride) {
      int p = atomicAdd(&cursor[dst[e]], 1);
      ssrc[p] = src[e];
    }
    return;
  }

  // ---- gemm0 part ----
  int gx = bx >> 1, y = bx & 1;
  {                                              // stage 64 KB = 4096 int4, 512 thr x 8
    const int4* s4 = (const int4*)(Bp + (size_t)y * 32768);
    int4* d4 = (int4*)Bs;
    #pragma unroll
    for (int i = 0; i < 8; ++i) d4[tid + i * 512] = s4[tid + i * 512];
  }
  __syncthreads();

  int wid = tid >> 6, lane = tid & 63;
  int quad = lane >> 4, col16 = lane & 15;
  int wr = wid >> 1, wc = wid & 1;               // 4 row-waves x 2 col-waves
  int rowbase = gx * 256 + wr * 64;

  // clamped row pointers (branch-free A loads; clamped rows only affect unwritten C-rows)
  const float* aptr[4];
  #pragma unroll
  for (int rt = 0; rt < 4; ++rt) {
    int m = rowbase + rt * 16 + col16;
    if (m > M - 1) m = M - 1;
    aptr[rt] = A + (size_t)m * 256 + quad * 8;
  }

  f32x4 acc[4][4];
  #pragma unroll
  for (int rt = 0; rt < 4; ++rt)
    #pragma unroll
    for (int ct = 0; ct < 4; ++ct) acc[rt][ct] = {0.f, 0.f, 0.f, 0.f};

  const bf16x8* BsV = (const bf16x8*)Bs;

  auto loadA = [&](bf16x8* fr, int s) {
    #pragma unroll
    for (int rt = 0; rt < 4; ++rt) {
      const float* ap = aptr[rt] + s * 32;
      float4 a0 = *(const float4*)ap;
      float4 a1 = *(const float4*)(ap + 4);
      fr[rt][0] = (short)f2bf(a0.x); fr[rt][1] = (short)f2bf(a0.y);
      fr[rt][2] = (short)f2bf(a0.z); fr[rt][3] = (short)f2bf(a0.w);
      fr[rt][4] = (short)f2bf(a1.x); fr[rt][5] = (short)f2bf(a1.y);
      fr[rt][6] = (short)f2bf(a1.z); fr[rt][7] = (short)f2bf(a1.w);
    }
  };

  bf16x8 afc[4];
  loadA(afc, 0);
  for (int s = 0; s < 8; ++s) {
    bf16x8 afn[4];
    if (s < 7) loadA(afn, s + 1);                // prefetch next k-step
    #pragma unroll
    for (int ct = 0; ct < 4; ++ct) {
      bf16x8 bf = BsV[((wc * 4 + ct) * 8 + s) * 64 + lane];
      #pragma unroll
      for (int rt = 0; rt < 4; ++rt)
        acc[rt][ct] = __builtin_amdgcn_mfma_f32_16x16x32_bf16(afc[rt], bf, acc[rt][ct], 0, 0, 0);
    }
    if (s < 7) {
      #pragma unroll
      for (int rt = 0; rt < 4; ++rt) afc[rt] = afn[rt];
    }
  }

  int hw = y * 2 + wc;
  float al_c[4], ar_c[4];
  #pragma unroll
  for (int ct = 0; ct < 4; ++ct) {
    int col = y * 128 + (wc * 4 + ct) * 16 + col16;
    al_c[ct] = al[col];
    ar_c[ct] = arr[col];
  }

  #pragma unroll
  for (int rt = 0; rt < 4; ++rt) {
    int row0 = rowbase + rt * 16 + quad * 4;
    #pragma unroll
    for (int r = 0; r < 4; ++r) {
      int row = row0 + r;
      if (row < M) {
        #pragma unroll
        for (int ct = 0; ct < 4; ++ct) {
          int col = y * 128 + (wc * 4 + ct) * 16 + col16;
          Zb[(size_t)row * 256 + col] = f2bf(acc[rt][ct][r]);
        }
      }
      float pe = 0.f, pr = 0.f;
      #pragma unroll
      for (int ct = 0; ct < 4; ++ct) {
        float zv = acc[rt][ct][r];
        pe += zv * al_c[ct];
        pr += zv * ar_c[ct];
      }
      pe += __shfl_xor(pe, 1); pr += __shfl_xor(pr, 1);
      pe += __shfl_xor(pe, 2); pr += __shfl_xor(pr, 2);
      pe += __shfl_xor(pe, 4); pr += __shfl_xor(pr, 4);
      pe += __shfl_xor(pe, 8); pr += __shfl_xor(pr, 8);
      if (col16 == 0 && row < M) {
        el[(size_t)row * 4 + hw] = pe;
        er[(size_t)row * 4 + hw] = pr;
      }
    }
  }
}

// ============================ layer-1 GEMM (proven R9) ============================

__global__ __launch_bounds__(256) void gemm1_mfma_kernel(
    const unsigned short* __restrict__ Ab, const unsigned short* __restrict__ Bp,
    unsigned short* __restrict__ Zb,
    const float* __restrict__ al, const float* __restrict__ arr,
    float* __restrict__ el, float* __restrict__ er, int M) {
  int wid = threadIdx.x >> 6, lane = threadIdx.x & 63;
  int quad = lane >> 4, col16 = lane & 15;
  int m = blockIdx.x * 64 + wid * 16 + col16;

  f32x4 acc[3];
  #pragma unroll
  for (int t = 0; t < 3; ++t) acc[t] = {0.f, 0.f, 0.f, 0.f};

  const bf16x8* BpV = (const bf16x8*)Bp;

  for (int s = 0; s < 8; ++s) {
    bf16x8 af;
    if (m < M) {
      af = *(const bf16x8*)(Ab + (size_t)m * 256 + s * 32 + quad * 8);
    } else {
      #pragma unroll
      for (int j = 0; j < 8; ++j) af[j] = 0;
    }
    #pragma unroll
    for (int t = 0; t < 3; ++t) {
      bf16x8 bf = BpV[(t * 8 + s) * 64 + lane];
      acc[t] = __builtin_amdgcn_mfma_f32_16x16x32_bf16(af, bf, acc[t], 0, 0, 0);
    }
  }

  float al_c[3], ar_c[3];
  #pragma unroll
  for (int t = 0; t < 3; ++t) {
    int col = t * 16 + col16;
    al_c[t] = (col < 40) ? al[col] : 0.f;
    ar_c[t] = (col < 40) ? arr[col] : 0.f;
  }

  int row0 = blockIdx.x * 64 + wid * 16 + quad * 4;
  #pragma unroll
  for (int r = 0; r < 4; ++r) {
    int row = row0 + r;
    if (row < M) {
      #pragma unroll
      for (int t = 0; t < 3; ++t) {
        int col = t * 16 + col16;
        if (col < 40) Zb[(size_t)row * 40 + col] = f2bf(acc[t][r]);
      }
    }
    float pe = 0.f, pr = 0.f;
    #pragma unroll
    for (int t = 0; t < 3; ++t) {
      pe += acc[t][r] * al_c[t];
      pr += acc[t][r] * ar_c[t];
    }
    pe += __shfl_xor(pe, 1); pr += __shfl_xor(pr, 1);
    pe += __shfl_xor(pe, 2); pr += __shfl_xor(pr, 2);
    pe += __shfl_xor(pe, 4); pr += __shfl_xor(pr, 4);
    pe += __shfl_xor(pe, 8); pr += __shfl_xor(pr, 8);
    if (col16 == 0 && row < M) {
      el[row] = pe;
      er[row] = pr;
    }
  }
}

// ============================ layer-0 aggregation v2: 4-deep load pipeline ============================
// z-gather was 2 x 16B loads in flight/wave (one per half) -> latency-bound at ~3.4 TB/s.
// Now j += 8: each half issues 4 predicated 16B loads back-to-back before any FMA
// (exec-masked tails fetch nothing), doubling memory-level parallelism.

__global__ __launch_bounds__(256) void agg0_kernel(
    const int* __restrict__ offs, const int* __restrict__ ssrc,
    const float* __restrict__ el, const float* __restrict__ er,
    const unsigned short* __restrict__ zb, const float* __restrict__ bias,
    unsigned short* __restrict__ outb, int n) {
  __shared__ float sW[4][16][4];
  __shared__ int   sS[4][16];
  int wid  = threadIdx.x >> 6;
  int lane = threadIdx.x & 63;
  int node = blockIdx.x * 4 + wid;
  if (node >= n) return;
  int c = lane & 3, eoff = lane >> 2;
  int half = lane >> 5, colg = lane & 31, h2 = colg >> 3;
  int s0 = offs[node], s1 = offs[node + 1];
  float er_c = er[node * 4 + c];
  const unsigned short* zcol = zb + (colg << 3);

  float ssum = 0.f;
  float acc[8] = {0.f, 0.f, 0.f, 0.f, 0.f, 0.f, 0.f, 0.f};
  for (int base = s0; base < s1; base += 16) {
    int cnt = min(16, s1 - base);
    if (eoff < cnt) {
      int esrc = ssrc[base + eoff];
      float v = el[esrc * 4 + c] + er_c;
      v = v > 0.f ? v : 0.2f * v;              // leaky_relu(0.2)
      sW[wid][eoff][c] = expf(v);              // no max-shift (scores O(+-10))
      if (c == 0) sS[wid][eoff] = esrc;
    }
    for (int j = 0; j < cnt; j += 8) {
      float w[4];
      bf16x8 zu[4];
      #pragma unroll
      for (int u = 0; u < 4; ++u) {
        int jj = j + 2 * u + half;
        if (jj < cnt) {
          w[u] = sW[wid][jj][h2];
          int sn = sS[wid][jj];
          zu[u] = *(const bf16x8*)(zcol + (size_t)sn * 256);
        } else {
          w[u] = 0.f;
          #pragma unroll
          for (int i = 0; i < 8; ++i) zu[u][i] = 0;
        }
      }
      #pragma unroll
      for (int u = 0; u < 4; ++u) {
        ssum += w[u];
        #pragma unroll
        for (int i = 0; i < 8; ++i)
          acc[i] += w[u] * bf2f((unsigned short)zu[u][i]);
      }
    }
  }

  ssum += __shfl_xor(ssum, 32);
  #pragma unroll
  for (int i = 0; i < 8; ++i) acc[i] += __shfl_xor(acc[i], 32);

  float inv = (s1 > s0) ? 1.f / ssum : 0.f;    // deg==0 -> out = bias
  if (half == 0) {
    const float4 b0v = *(const float4*)(bias + (colg << 3));
    const float4 b1v = *(const float4*)(bias + (colg << 3) + 4);
    float bb[8] = {b0v.x, b0v.y, b0v.z, b0v.w, b1v.x, b1v.y, b1v.z, b1v.w};
    bf16x8 u;
    #pragma unroll
    for (int i = 0; i < 8; ++i) {
      float o = acc[i] * inv + bb[i];
      o = o > 0.f ? o : expm1f(o);             // ELU
      u[i] = (short)f2bf(o);
    }
    *(bf16x8*)(outb + (size_t)node * 256 + (colg << 3)) = u;
  }
}

// ============================ layer-1 aggregation (proven R12) ============================

__global__ __launch_bounds__(256) void agg1_kernel(
    const int* __restrict__ offs, const int* __restrict__ ssrc,
    const float* __restrict__ el, const float* __restrict__ er,
    const unsigned short* __restrict__ zb, const float* __restrict__ bias,
    float* __restrict__ out, int n) {
  __shared__ float sW[4][64];
  __shared__ int   sS[4][64];
  int wid  = threadIdx.x >> 6;
  int lane = threadIdx.x & 63;
  int node = blockIdx.x * 4 + wid;
  if (node >= n) return;
  int half = lane >> 5, d = lane & 31;
  int s0 = offs[node], s1 = offs[node + 1];
  float ern = er[node];

  float ssum = 0.f;
  float2 acc = make_float2(0.f, 0.f);
  for (int base = s0; base < s1; base += 64) {
    int cnt = min(64, s1 - base);
    if (lane < cnt) {
      int esrc = ssrc[base + lane];
      float v = el[esrc] + ern;
      v = v > 0.f ? v : 0.2f * v;
      sW[wid][lane] = expf(v);                 // no max-shift
      sS[wid][lane] = esrc;
    }
    for (int j = 0; j < cnt; j += 2) {
      int jj = j + half;
      float w = (jj < cnt) ? sW[wid][jj] : 0.f;
      int sn = sS[wid][(jj < cnt) ? jj : (cnt - 1)];
      ssum += w;
      if (d < 20) {
        unsigned zp = *(const unsigned*)(zb + (size_t)sn * 40 + (d << 1));
        acc.x += w * bf2f((unsigned short)(zp & 0xffffu));
        acc.y += w * bf2f((unsigned short)(zp >> 16));
      }
    }
  }

  ssum  += __shfl_xor(ssum, 32);
  acc.x += __shfl_xor(acc.x, 32);
  acc.y += __shfl_xor(acc.y, 32);

  float inv = (s1 > s0) ? 1.f / ssum : 0.f;
  if (half == 0 && d < 20) {
    float2 o;
    o.x = acc.x * inv + bias[(d << 1) + 0];
    o.y = acc.y * inv + bias[(d << 1) + 1];
    *(float2*)(out + (size_t)node * 40 + (d << 1)) = o;
  }
}

// ============================ launch ============================

extern "C" void kernel_launch(void* const* d_in, const int* in_sizes, int n_in,
                              void* d_out, int out_size, void* d_ws, size_t ws_size,
                              hipStream_t stream) {
  const float* x   = (const float*)d_in[0];
  const int*   src = (const int*)d_in[1];
  const int*   dst = (const int*)d_in[2];
  const float* W0  = (const float*)d_in[3];
  const float* al0 = (const float*)d_in[4];
  const float* ar0 = (const float*)d_in[5];
  const float* b0  = (const float*)d_in[6];
  const float* W1  = (const float*)d_in[7];
  const float* al1 = (const float*)d_in[8];
  const float* ar1 = (const float*)d_in[9];
  const float* b1  = (const float*)d_in[10];
  float* out = (float*)d_out;

  const int N = in_sizes[0] / 256;   // 50000
  const int E = in_sizes[1];         // 800000
  const int NB = (N + 255) / 256;    // 196 scan blocks

  char* ws = (char*)d_ws;
  size_t off = 0;
  auto alloc = [&](size_t bytes) {
    void* p = ws + off;
    off = (off + bytes + 255) & ~(size_t)255;
    return p;
  };
  unsigned short* z0b = (unsigned short*)alloc((size_t)N * 256 * 2);
  unsigned short* h0b = (unsigned short*)alloc((size_t)N * 256 * 2);
  unsigned short* z1b = (unsigned short*)alloc((size_t)N * 40 * 2);
  unsigned short* w0p = (unsigned short*)alloc((size_t)16 * 8 * 64 * 8 * 2);
  unsigned short* w1p = (unsigned short*)alloc((size_t)3 * 8 * 64 * 8 * 2);
  float* el0  = (float*)alloc((size_t)N * 4 * 4);
  float* er0  = (float*)alloc((size_t)N * 4 * 4);
  float* el1  = (float*)alloc((size_t)N * 4);
  float* er1  = (float*)alloc((size_t)N * 4);
  int* deg    = (int*)alloc((size_t)N * 4);
  int* offs   = (int*)alloc((size_t)(N + 1) * 4);
  int* cursor = (int*)alloc((size_t)N * 4);
  int* bsum   = (int*)alloc((size_t)NB * 4);
  int* boffs  = (int*)alloc((size_t)NB * 4);
  int* ssrc   = (int*)alloc((size_t)E * 4);
  (void)off; (void)ws_size; (void)n_in; (void)out_size;

  const int nG = ((N + 255) / 256) * 2;          // 392 gemm0 blocks (256 rows x col-half)
  const int nH = (E + 255) / 256;                // 3125 hist blocks
  const int nC = 391;                            // csr blocks (512 thr, ~4 edges/thread)

  // 1. deg = 0
  hipMemsetAsync(deg, 0, (size_t)N * 4, stream);
  // 2. pack || hist (no LDS -> full occupancy)
  mega0_kernel<<<38 + nH, 256, 0, stream>>>(W0, w0p, W1, w1p, dst, deg, E);
  // 3-5. exclusive scan, 3-phase
  block_sum_kernel<<<NB, 256, 0, stream>>>(deg, bsum, N);
  scan_bsum_kernel<<<1, 1024, 0, stream>>>(bsum, boffs, offs, NB, N);
  write_offsets_kernel<<<NB, 256, 0, stream>>>(deg, boffs, offs, cursor, N);
  // 6. gemm0 || build_csr (exact R0 fused kernel, proven 72us)
  mega2_kernel<<<nG + nC, 512, 0, stream>>>(x, w0p, z0b, al0, ar0, el0, er0, N,
                                            src, dst, cursor, ssrc, E, nG, nC);
  // 7. layer-0 aggregation + ELU -> h0b (4-deep load pipeline)
  agg0_kernel<<<(N + 3) / 4, 256, 0, stream>>>(offs, ssrc, el0, er0, z0b, b0, h0b, N);
  // 8. layer-1 GEMM + fused el/er
  gemm1_mfma_kernel<<<(N + 63) / 64, 256, 0, stream>>>(h0b, w1p, z1b, al1, ar1, el1, er1, N);
  // 9. layer-1 aggregation -> out
  agg1_kernel<<<(N + 3) / 4, 256, 0, stream>>>(offs, ssrc, el1, er1, z1b, b1, out, N);
}

// Round 7
// 315.447 us; speedup vs baseline: 1.1016x; 1.0084x over previous
//
#include <hip/hip_runtime.h>
#include <math.h>

using bf16x8 = __attribute__((ext_vector_type(8))) short;
using f32x4  = __attribute__((ext_vector_type(4))) float;

// ---- bf16 helpers ----
__device__ __forceinline__ unsigned short f2bf(float v) {          // RNE pack
  unsigned int b = __float_as_uint(v);
  unsigned int r = (b + 0x7fffu + ((b >> 16) & 1u)) >> 16;
  return (unsigned short)r;
}
__device__ __forceinline__ float bf2f(unsigned short u) {
  return __uint_as_float(((unsigned int)u) << 16);
}

// ============================ mega0: pack (blocks 0..37) || hist (blocks 38..) (proven R16) ============================

__global__ void mega0_kernel(const float* __restrict__ W0f, unsigned short* __restrict__ Bp0,
                             const float* __restrict__ W1f, unsigned short* __restrict__ Bp1,
                             const int* __restrict__ dst, int* __restrict__ deg, int E) {
  int bx = blockIdx.x;
  if (bx >= 38) {                                // ---- hist ----
    int t = (bx - 38) * 256 + threadIdx.x;
    if (t < E) atomicAdd(&deg[dst[t]], 1);
    return;
  }
  int idx = bx * 256 + threadIdx.x;
  if (idx < 8192) {
    int lane = idx & 63, s = (idx >> 6) & 7, t = idx >> 9;
    int n = t * 16 + (lane & 15), quad = lane >> 4;
    unsigned short* o = Bp0 + (size_t)idx * 8;
    #pragma unroll
    for (int j = 0; j < 8; ++j) {
      int k = s * 32 + quad * 8 + j;
      o[j] = f2bf(W0f[(size_t)k * 256 + n]);
    }
  } else if (idx < 8192 + 1536) {
    int i1 = idx - 8192;
    int lane = i1 & 63, s = (i1 >> 6) & 7, t = i1 >> 9;
    int n = t * 16 + (lane & 15), quad = lane >> 4;
    unsigned short* o = Bp1 + (size_t)i1 * 8;
    #pragma unroll
    for (int j = 0; j < 8; ++j) {
      int k = s * 32 + quad * 8 + j;
      o[j] = (n < 40) ? f2bf(W1f[(size_t)k * 40 + n]) : 0;
    }
  }
}

// ============================ 3-phase parallel scan (proven R5-R16) ============================

__global__ void block_sum_kernel(const int* __restrict__ deg, int* __restrict__ bsum, int n) {
  __shared__ int red[4];
  int t = threadIdx.x, i = blockIdx.x * 256 + t;
  int v = (i < n) ? deg[i] : 0;
  #pragma unroll
  for (int off = 32; off; off >>= 1) v += __shfl_xor(v, off);
  if ((t & 63) == 0) red[t >> 6] = v;
  __syncthreads();
  if (t == 0) bsum[blockIdx.x] = red[0] + red[1] + red[2] + red[3];
}

__global__ void scan_bsum_kernel(const int* __restrict__ bsum, int* __restrict__ boffs,
                                 int* __restrict__ offsets, int nb, int n) {
  __shared__ int tmp[1024];
  int t = threadIdx.x;
  int v = (t < nb) ? bsum[t] : 0;
  tmp[t] = v;
  __syncthreads();
  #pragma unroll
  for (int off = 1; off < 1024; off <<= 1) {
    int add = (t >= off) ? tmp[t - off] : 0;
    __syncthreads();
    tmp[t] += add;
    __syncthreads();
  }
  if (t < nb) boffs[t] = tmp[t] - v;
  if (t == 1023) offsets[n] = tmp[1023];
}

__global__ void write_offsets_kernel(const int* __restrict__ deg, const int* __restrict__ boffs,
                                     int* __restrict__ offsets, int* __restrict__ cursor, int n) {
  __shared__ int tmp[256];
  int t = threadIdx.x, i = blockIdx.x * 256 + t;
  int v = (i < n) ? deg[i] : 0;
  tmp[t] = v;
  __syncthreads();
  #pragma unroll
  for (int off = 1; off < 256; off <<= 1) {
    int add = (t >= off) ? tmp[t - off] : 0;
    __syncthreads();
    tmp[t] += add;
    __syncthreads();
  }
  if (i < n) {
    int o = boffs[blockIdx.x] + tmp[t] - v;
    offsets[i] = o;
    cursor[i] = o;
  }
}

// ============================ mega2 v6: 128r x 128c blocks, 32 KB LDS, 32-AGPR acc ============================
// Same fused gemm||csr and col-HALF split as the proven R0 kernel (FETCH unchanged), but:
//  - block = 128 rows x 128 cols, 8 waves (4 row x 2 col), wave = 32r x 64c -> acc 2x4 = 32 AGPR
//  - B staged in two 32 KB K-halves (restaged mid-loop) -> LDS 32 KB
//  - regs ~80/wave + LDS 32 KB -> ~3 blocks/CU = 24 waves/CU (vs 16), 1.5x latency hiding
// csr part (bx >= nG): unchanged grid-stride scatter.

__global__ __launch_bounds__(512) void mega2_kernel(
    const float* __restrict__ A, const unsigned short* __restrict__ Bp,
    unsigned short* __restrict__ Zb,
    const float* __restrict__ al, const float* __restrict__ arr,
    float* __restrict__ el, float* __restrict__ er, int M,
    const int* __restrict__ src, const int* __restrict__ dst,
    int* __restrict__ cursor, int* __restrict__ ssrc, int E, int nG, int nC) {
  __shared__ unsigned short Bs[16384];           // 32 KB: one K-half of this col-half of W0
  int bx = blockIdx.x;
  int tid = threadIdx.x;

  if (bx >= nG) {                                // ---- build_csr part ----
    int stride = nC * 512;
    for (int e = (bx - nG) * 512 + tid; e < E; e += stride) {
      int p = atomicAdd(&cursor[dst[e]], 1);
      ssrc[p] = src[e];
    }
    return;
  }

  // ---- gemm0 part ----
  int gx = bx >> 1, y = bx & 1;                  // row group of 128, col half
  int wid = tid >> 6, lane = tid & 63;
  int quad = lane >> 4, col16 = lane & 15;
  int wr = wid >> 1, wc = wid & 1;               // 4 row-waves x 2 col-waves
  int rowbase = gx * 128 + wr * 32;

  // clamped row pointers (branch-free A loads; clamped rows only affect unwritten C-rows)
  const float* aptr[2];
  #pragma unroll
  for (int rt = 0; rt < 2; ++rt) {
    int m = rowbase + rt * 16 + col16;
    if (m > M - 1) m = M - 1;
    aptr[rt] = A + (size_t)m * 256 + quad * 8;
  }

  auto loadA = [&](bf16x8* fr, int s) {
    #pragma unroll
    for (int rt = 0; rt < 2; ++rt) {
      const float* ap = aptr[rt] + s * 32;
      float4 a0 = *(const float4*)ap;
      float4 a1 = *(const float4*)(ap + 4);
      fr[rt][0] = (short)f2bf(a0.x); fr[rt][1] = (short)f2bf(a0.y);
      fr[rt][2] = (short)f2bf(a0.z); fr[rt][3] = (short)f2bf(a0.w);
      fr[rt][4] = (short)f2bf(a1.x); fr[rt][5] = (short)f2bf(a1.y);
      fr[rt][6] = (short)f2bf(a1.z); fr[rt][7] = (short)f2bf(a1.w);
    }
  };

  f32x4 acc[2][4];
  #pragma unroll
  for (int rt = 0; rt < 2; ++rt)
    #pragma unroll
    for (int ct = 0; ct < 4; ++ct) acc[rt][ct] = {0.f, 0.f, 0.f, 0.f};

  const bf16x8* BsV = (const bf16x8*)Bs;
  const int4* s4 = (const int4*)Bp;
  int4* d4 = (int4*)Bs;

  // first k-step A loads issued before staging: latency hides under copy + barrier
  bf16x8 afc[2];
  loadA(afc, 0);

  for (int h = 0; h < 2; ++h) {
    if (h) __syncthreads();                      // all waves done reading K-half 0
    // stage 32 KB = 2048 frags (int4); frag f = ct_local*256 + srel*64 + ln
    #pragma unroll
    for (int j = 0; j < 4; ++j) {
      int f = tid + j * 512;
      int ct_l = f >> 8, r = f & 255;
      d4[f] = s4[y * 4096 + ct_l * 512 + h * 256 + r];
    }
    __syncthreads();

    #pragma unroll
    for (int srel = 0; srel < 4; ++srel) {
      int s = h * 4 + srel;
      bf16x8 afn[2];
      if (s < 7) loadA(afn, s + 1);              // prefetch next k-step
      #pragma unroll
      for (int ct = 0; ct < 4; ++ct) {
        bf16x8 bf = BsV[((wc * 4 + ct) * 4 + srel) * 64 + lane];
        #pragma unroll
        for (int rt = 0; rt < 2; ++rt)
          acc[rt][ct] = __builtin_amdgcn_mfma_f32_16x16x32_bf16(afc[rt], bf, acc[rt][ct], 0, 0, 0);
      }
      if (s < 7) {
        #pragma unroll
        for (int rt = 0; rt < 2; ++rt) afc[rt] = afn[rt];
      }
    }
  }

  int hw = y * 2 + wc;                           // this col-wave's 64 cols = head hw
  float al_c[4], ar_c[4];
  #pragma unroll
  for (int ct = 0; ct < 4; ++ct) {
    int col = y * 128 + wc * 64 + ct * 16 + col16;
    al_c[ct] = al[col];
    ar_c[ct] = arr[col];
  }

  #pragma unroll
  for (int rt = 0; rt < 2; ++rt) {
    int row0 = rowbase + rt * 16 + quad * 4;
    #pragma unroll
    for (int r = 0; r < 4; ++r) {
      int row = row0 + r;
      if (row < M) {
        #pragma unroll
        for (int ct = 0; ct < 4; ++ct) {
          int col = y * 128 + wc * 64 + ct * 16 + col16;
          Zb[(size_t)row * 256 + col] = f2bf(acc[rt][ct][r]);
        }
      }
      float pe = 0.f, pr = 0.f;
      #pragma unroll
      for (int ct = 0; ct < 4; ++ct) {
        float zv = acc[rt][ct][r];
        pe += zv * al_c[ct];
        pr += zv * ar_c[ct];
      }
      pe += __shfl_xor(pe, 1); pr += __shfl_xor(pr, 1);
      pe += __shfl_xor(pe, 2); pr += __shfl_xor(pr, 2);
      pe += __shfl_xor(pe, 4); pr += __shfl_xor(pr, 4);
      pe += __shfl_xor(pe, 8); pr += __shfl_xor(pr, 8);
      if (col16 == 0 && row < M) {
        el[(size_t)row * 4 + hw] = pe;
        er[(size_t)row * 4 + hw] = pr;
      }
    }
  }
}

// ============================ layer-1 GEMM (proven R9) ============================

__global__ __launch_bounds__(256) void gemm1_mfma_kernel(
    const unsigned short* __restrict__ Ab, const unsigned short* __restrict__ Bp,
    unsigned short* __restrict__ Zb,
    const float* __restrict__ al, const float* __restrict__ arr,
    float* __restrict__ el, float* __restrict__ er, int M) {
  int wid = threadIdx.x >> 6, lane = threadIdx.x & 63;
  int quad = lane >> 4, col16 = lane & 15;
  int m = blockIdx.x * 64 + wid * 16 + col16;

  f32x4 acc[3];
  #pragma unroll
  for (int t = 0; t < 3; ++t) acc[t] = {0.f, 0.f, 0.f, 0.f};

  const bf16x8* BpV = (const bf16x8*)Bp;

  for (int s = 0; s < 8; ++s) {
    bf16x8 af;
    if (m < M) {
      af = *(const bf16x8*)(Ab + (size_t)m * 256 + s * 32 + quad * 8);
    } else {
      #pragma unroll
      for (int j = 0; j < 8; ++j) af[j] = 0;
    }
    #pragma unroll
    for (int t = 0; t < 3; ++t) {
      bf16x8 bf = BpV[(t * 8 + s) * 64 + lane];
      acc[t] = __builtin_amdgcn_mfma_f32_16x16x32_bf16(af, bf, acc[t], 0, 0, 0);
    }
  }

  float al_c[3], ar_c[3];
  #pragma unroll
  for (int t = 0; t < 3; ++t) {
    int col = t * 16 + col16;
    al_c[t] = (col < 40) ? al[col] : 0.f;
    ar_c[t] = (col < 40) ? arr[col] : 0.f;
  }

  int row0 = blockIdx.x * 64 + wid * 16 + quad * 4;
  #pragma unroll
  for (int r = 0; r < 4; ++r) {
    int row = row0 + r;
    if (row < M) {
      #pragma unroll
      for (int t = 0; t < 3; ++t) {
        int col = t * 16 + col16;
        if (col < 40) Zb[(size_t)row * 40 + col] = f2bf(acc[t][r]);
      }
    }
    float pe = 0.f, pr = 0.f;
    #pragma unroll
    for (int t = 0; t < 3; ++t) {
      pe += acc[t][r] * al_c[t];
      pr += acc[t][r] * ar_c[t];
    }
    pe += __shfl_xor(pe, 1); pr += __shfl_xor(pr, 1);
    pe += __shfl_xor(pe, 2); pr += __shfl_xor(pr, 2);
    pe += __shfl_xor(pe, 4); pr += __shfl_xor(pr, 4);
    pe += __shfl_xor(pe, 8); pr += __shfl_xor(pr, 8);
    if (col16 == 0 && row < M) {
      el[row] = pe;
      er[row] = pr;
    }
  }
}

// ============================ layer-0 aggregation (R6 form) ============================

__global__ __launch_bounds__(256) void agg0_kernel(
    const int* __restrict__ offs, const int* __restrict__ ssrc,
    const float* __restrict__ el, const float* __restrict__ er,
    const unsigned short* __restrict__ zb, const float* __restrict__ bias,
    unsigned short* __restrict__ outb, int n) {
  __shared__ float sW[4][16][4];
  __shared__ int   sS[4][16];
  int wid  = threadIdx.x >> 6;
  int lane = threadIdx.x & 63;
  int node = blockIdx.x * 4 + wid;
  if (node >= n) return;
  int c = lane & 3, eoff = lane >> 2;
  int half = lane >> 5, colg = lane & 31, h2 = colg >> 3;
  int s0 = offs[node], s1 = offs[node + 1];
  float er_c = er[node * 4 + c];
  const unsigned short* zcol = zb + (colg << 3);

  float ssum = 0.f;
  float acc[8] = {0.f, 0.f, 0.f, 0.f, 0.f, 0.f, 0.f, 0.f};
  for (int base = s0; base < s1; base += 16) {
    int cnt = min(16, s1 - base);
    if (eoff < cnt) {
      int esrc = ssrc[base + eoff];
      float v = el[esrc * 4 + c] + er_c;
      v = v > 0.f ? v : 0.2f * v;              // leaky_relu(0.2)
      sW[wid][eoff][c] = expf(v);              // no max-shift (scores O(+-10))
      if (c == 0) sS[wid][eoff] = esrc;
    }
    for (int j = 0; j < cnt; j += 8) {
      float w[4];
      bf16x8 zu[4];
      #pragma unroll
      for (int u = 0; u < 4; ++u) {
        int jj = j + 2 * u + half;
        if (jj < cnt) {
          w[u] = sW[wid][jj][h2];
          int sn = sS[wid][jj];
          zu[u] = *(const bf16x8*)(zcol + (size_t)sn * 256);
        } else {
          w[u] = 0.f;
          #pragma unroll
          for (int i = 0; i < 8; ++i) zu[u][i] = 0;
        }
      }
      #pragma unroll
      for (int u = 0; u < 4; ++u) {
        ssum += w[u];
        #pragma unroll
        for (int i = 0; i < 8; ++i)
          acc[i] += w[u] * bf2f((unsigned short)zu[u][i]);
      }
    }
  }

  ssum += __shfl_xor(ssum, 32);
  #pragma unroll
  for (int i = 0; i < 8; ++i) acc[i] += __shfl_xor(acc[i], 32);

  float inv = (s1 > s0) ? 1.f / ssum : 0.f;    // deg==0 -> out = bias
  if (half == 0) {
    const float4 b0v = *(const float4*)(bias + (colg << 3));
    const float4 b1v = *(const float4*)(bias + (colg << 3) + 4);
    float bb[8] = {b0v.x, b0v.y, b0v.z, b0v.w, b1v.x, b1v.y, b1v.z, b1v.w};
    bf16x8 u;
    #pragma unroll
    for (int i = 0; i < 8; ++i) {
      float o = acc[i] * inv + bb[i];
      o = o > 0.f ? o : expm1f(o);             // ELU
      u[i] = (short)f2bf(o);
    }
    *(bf16x8*)(outb + (size_t)node * 256 + (colg << 3)) = u;
  }
}

// ============================ layer-1 aggregation (proven R12) ============================

__global__ __launch_bounds__(256) void agg1_kernel(
    const int* __restrict__ offs, const int* __restrict__ ssrc,
    const float* __restrict__ el, const float* __restrict__ er,
    const unsigned short* __restrict__ zb, const float* __restrict__ bias,
    float* __restrict__ out, int n) {
  __shared__ float sW[4][64];
  __shared__ int   sS[4][64];
  int wid  = threadIdx.x >> 6;
  int lane = threadIdx.x & 63;
  int node = blockIdx.x * 4 + wid;
  if (node >= n) return;
  int half = lane >> 5, d = lane & 31;
  int s0 = offs[node], s1 = offs[node + 1];
  float ern = er[node];

  float ssum = 0.f;
  float2 acc = make_float2(0.f, 0.f);
  for (int base = s0; base < s1; base += 64) {
    int cnt = min(64, s1 - base);
    if (lane < cnt) {
      int esrc = ssrc[base + lane];
      float v = el[esrc] + ern;
      v = v > 0.f ? v : 0.2f * v;
      sW[wid][lane] = expf(v);                 // no max-shift
      sS[wid][lane] = esrc;
    }
    for (int j = 0; j < cnt; j += 2) {
      int jj = j + half;
      float w = (jj < cnt) ? sW[wid][jj] : 0.f;
      int sn = sS[wid][(jj < cnt) ? jj : (cnt - 1)];
      ssum += w;
      if (d < 20) {
        unsigned zp = *(const unsigned*)(zb + (size_t)sn * 40 + (d << 1));
        acc.x += w * bf2f((unsigned short)(zp & 0xffffu));
        acc.y += w * bf2f((unsigned short)(zp >> 16));
      }
    }
  }

  ssum  += __shfl_xor(ssum, 32);
  acc.x += __shfl_xor(acc.x, 32);
  acc.y += __shfl_xor(acc.y, 32);

  float inv = (s1 > s0) ? 1.f / ssum : 0.f;
  if (half == 0 && d < 20) {
    float2 o;
    o.x = acc.x * inv + bias[(d << 1) + 0];
    o.y = acc.y * inv + bias[(d << 1) + 1];
    *(float2*)(out + (size_t)node * 40 + (d << 1)) = o;
  }
}

// ============================ launch ============================

extern "C" void kernel_launch(void* const* d_in, const int* in_sizes, int n_in,
                              void* d_out, int out_size, void* d_ws, size_t ws_size,
                              hipStream_t stream) {
  const float* x   = (const float*)d_in[0];
  const int*   src = (const int*)d_in[1];
  const int*   dst = (const int*)d_in[2];
  const float* W0  = (const float*)d_in[3];
  const float* al0 = (const float*)d_in[4];
  const float* ar0 = (const float*)d_in[5];
  const float* b0  = (const float*)d_in[6];
  const float* W1  = (const float*)d_in[7];
  const float* al1 = (const float*)d_in[8];
  const float* ar1 = (const float*)d_in[9];
  const float* b1  = (const float*)d_in[10];
  float* out = (float*)d_out;

  const int N = in_sizes[0] / 256;   // 50000
  const int E = in_sizes[1];         // 800000
  const int NB = (N + 255) / 256;    // 196 scan blocks

  char* ws = (char*)d_ws;
  size_t off = 0;
  auto alloc = [&](size_t bytes) {
    void* p = ws + off;
    off = (off + bytes + 255) & ~(size_t)255;
    return p;
  };
  unsigned short* z0b = (unsigned short*)alloc((size_t)N * 256 * 2);
  unsigned short* h0b = (unsigned short*)alloc((size_t)N * 256 * 2);
  unsigned short* z1b = (unsigned short*)alloc((size_t)N * 40 * 2);
  unsigned short* w0p = (unsigned short*)alloc((size_t)16 * 8 * 64 * 8 * 2);
  unsigned short* w1p = (unsigned short*)alloc((size_t)3 * 8 * 64 * 8 * 2);
  float* el0  = (float*)alloc((size_t)N * 4 * 4);
  float* er0  = (float*)alloc((size_t)N * 4 * 4);
  float* el1  = (float*)alloc((size_t)N * 4);
  float* er1  = (float*)alloc((size_t)N * 4);
  int* deg    = (int*)alloc((size_t)N * 4);
  int* offs   = (int*)alloc((size_t)(N + 1) * 4);
  int* cursor = (int*)alloc((size_t)N * 4);
  int* bsum   = (int*)alloc((size_t)NB * 4);
  int* boffs  = (int*)alloc((size_t)NB * 4);
  int* ssrc   = (int*)alloc((size_t)E * 4);
  (void)off; (void)ws_size; (void)n_in; (void)out_size;

  const int nG = ((N + 127) / 128) * 2;          // 782 gemm0 blocks (128 rows x col-half)
  const int nH = (E + 255) / 256;                // 3125 hist blocks
  const int nC = 391;                            // csr blocks (512 thr, ~4 edges/thread)

  // 1. deg = 0
  hipMemsetAsync(deg, 0, (size_t)N * 4, stream);
  // 2. pack || hist (no LDS -> full occupancy)
  mega0_kernel<<<38 + nH, 256, 0, stream>>>(W0, w0p, W1, w1p, dst, deg, E);
  // 3-5. exclusive scan, 3-phase
  block_sum_kernel<<<NB, 256, 0, stream>>>(deg, bsum, N);
  scan_bsum_kernel<<<1, 1024, 0, stream>>>(bsum, boffs, offs, NB, N);
  write_offsets_kernel<<<NB, 256, 0, stream>>>(deg, boffs, offs, cursor, N);
  // 6. gemm0 || build_csr, 128r x 128c blocks, 32 KB LDS, ~3 blocks/CU
  mega2_kernel<<<nG + nC, 512, 0, stream>>>(x, w0p, z0b, al0, ar0, el0, er0, N,
                                            src, dst, cursor, ssrc, E, nG, nC);
  // 7. layer-0 aggregation + ELU -> h0b
  agg0_kernel<<<(N + 3) / 4, 256, 0, stream>>>(offs, ssrc, el0, er0, z0b, b0, h0b, N);
  // 8. layer-1 GEMM + fused el/er
  gemm1_mfma_kernel<<<(N + 63) / 64, 256, 0, stream>>>(h0b, w1p, z1b, al1, ar1, el1, er1, N);
  // 9. layer-1 aggregation -> out
  agg1_kernel<<<(N + 3) / 4, 256, 0, stream>>>(offs, ssrc, el1, er1, z1b, b1, out, N);
}

// Round 9
// 314.345 us; speedup vs baseline: 1.1054x; 1.0035x over previous
//
#include <hip/hip_runtime.h>
#include <math.h>

using bf16x8 = __attribute__((ext_vector_type(8))) short;
using f32x4  = __attribute__((ext_vector_type(4))) float;

// ---- bf16 helpers ----
__device__ __forceinline__ unsigned short f2bf(float v) {          // RNE pack
  unsigned int b = __float_as_uint(v);
  unsigned int r = (b + 0x7fffu + ((b >> 16) & 1u)) >> 16;
  return (unsigned short)r;
}
__device__ __forceinline__ float bf2f(unsigned short u) {
  return __uint_as_float(((unsigned int)u) << 16);
}

// ============================ mega0: pack (blocks 0..37) || hist (blocks 38..) (proven R16) ============================

__global__ void mega0_kernel(const float* __restrict__ W0f, unsigned short* __restrict__ Bp0,
                             const float* __restrict__ W1f, unsigned short* __restrict__ Bp1,
                             const int* __restrict__ dst, int* __restrict__ deg, int E) {
  int bx = blockIdx.x;
  if (bx >= 38) {                                // ---- hist ----
    int t = (bx - 38) * 256 + threadIdx.x;
    if (t < E) atomicAdd(&deg[dst[t]], 1);
    return;
  }
  int idx = bx * 256 + threadIdx.x;
  if (idx < 8192) {
    int lane = idx & 63, s = (idx >> 6) & 7, t = idx >> 9;
    int n = t * 16 + (lane & 15), quad = lane >> 4;
    unsigned short* o = Bp0 + (size_t)idx * 8;
    #pragma unroll
    for (int j = 0; j < 8; ++j) {
      int k = s * 32 + quad * 8 + j;
      o[j] = f2bf(W0f[(size_t)k * 256 + n]);
    }
  } else if (idx < 8192 + 1536) {
    int i1 = idx - 8192;
    int lane = i1 & 63, s = (i1 >> 6) & 7, t = i1 >> 9;
    int n = t * 16 + (lane & 15), quad = lane >> 4;
    unsigned short* o = Bp1 + (size_t)i1 * 8;
    #pragma unroll
    for (int j = 0; j < 8; ++j) {
      int k = s * 32 + quad * 8 + j;
      o[j] = (n < 40) ? f2bf(W1f[(size_t)k * 40 + n]) : 0;
    }
  }
}

// ============================ 3-phase parallel scan (proven R5-R16) ============================

__global__ void block_sum_kernel(const int* __restrict__ deg, int* __restrict__ bsum, int n) {
  __shared__ int red[4];
  int t = threadIdx.x, i = blockIdx.x * 256 + t;
  int v = (i < n) ? deg[i] : 0;
  #pragma unroll
  for (int off = 32; off; off >>= 1) v += __shfl_xor(v, off);
  if ((t & 63) == 0) red[t >> 6] = v;
  __syncthreads();
  if (t == 0) bsum[blockIdx.x] = red[0] + red[1] + red[2] + red[3];
}

__global__ void scan_bsum_kernel(const int* __restrict__ bsum, int* __restrict__ boffs,
                                 int* __restrict__ offsets, int nb, int n) {
  __shared__ int tmp[1024];
  int t = threadIdx.x;
  int v = (t < nb) ? bsum[t] : 0;
  tmp[t] = v;
  __syncthreads();
  #pragma unroll
  for (int off = 1; off < 1024; off <<= 1) {
    int add = (t >= off) ? tmp[t - off] : 0;
    __syncthreads();
    tmp[t] += add;
    __syncthreads();
  }
  if (t < nb) boffs[t] = tmp[t] - v;
  if (t == 1023) offsets[n] = tmp[1023];
}

__global__ void write_offsets_kernel(const int* __restrict__ deg, const int* __restrict__ boffs,
                                     int* __restrict__ offsets, int* __restrict__ cursor, int n) {
  __shared__ int tmp[256];
  int t = threadIdx.x, i = blockIdx.x * 256 + t;
  int v = (i < n) ? deg[i] : 0;
  tmp[t] = v;
  __syncthreads();
  #pragma unroll
  for (int off = 1; off < 256; off <<= 1) {
    int add = (t >= off) ? tmp[t - off] : 0;
    __syncthreads();
    tmp[t] += add;
    __syncthreads();
  }
  if (i < n) {
    int o = boffs[blockIdx.x] + tmp[t] - v;
    offsets[i] = o;
    cursor[i] = o;
  }
}

// ============================ mega2 v7: LDS-staged A (coalesced), 128r x 128c ============================
// The R0-R7 gemm loaded A fragments directly from global: 16 lanes x 16 different rows
// (1 KB stride) per instruction = ~32 scattered lines -> TA address-divergence serialization
// (the invisible floor: all PMC pipes idle). Now A is staged through LDS with row-major
// COALESCED loads (4 rows x 256 B contiguous per wave-instr), f32->bf16 on the fly, and
// fragments read from LDS with XOR-swizzled 16B slots (slot ^= row&7 -> free 2-way conflict).
// Geometry: 128 rows x 128 cols (col-half y), 512 thr, 8 waves (4r x 2c), acc 2x4 = 32 AGPR.
// LDS = As 32 KB + Bs 32 KB (K-halves restaged) = 64 KB -> 2 blocks/CU.
// csr part (bx >= nG): unchanged grid-stride scatter.

__global__ __launch_bounds__(512) void mega2_kernel(
    const float* __restrict__ A, const unsigned short* __restrict__ Bp,
    unsigned short* __restrict__ Zb,
    const float* __restrict__ al, const float* __restrict__ arr,
    float* __restrict__ el, float* __restrict__ er, int M,
    const int* __restrict__ src, const int* __restrict__ dst,
    int* __restrict__ cursor, int* __restrict__ ssrc, int E, int nG, int nC) {
  __shared__ unsigned short As[16384];           // 32 KB: 128 rows x 128 k (bf16, swizzled slots)
  __shared__ unsigned short Bs[16384];           // 32 KB: one K-half of this col-half of W0
  int bx = blockIdx.x;
  int tid = threadIdx.x;

  if (bx >= nG) {                                // ---- build_csr part ----
    int stride = nC * 512;
    for (int e = (bx - nG) * 512 + tid; e < E; e += stride) {
      int p = atomicAdd(&cursor[dst[e]], 1);
      ssrc[p] = src[e];
    }
    return;
  }

  // ---- gemm0 part ----
  int gx = bx >> 1, y = bx & 1;                  // row group of 128, col half
  int wid = tid >> 6, lane = tid & 63;
  int quad = lane >> 4, col16 = lane & 15;
  int wr = wid >> 1, wc = wid & 1;               // 4 row-waves x 2 col-waves
  int rowbase_l = wr * 32;                       // local row base (0..127)

  f32x4 acc[2][4];
  #pragma unroll
  for (int rt = 0; rt < 2; ++rt)
    #pragma unroll
    for (int ct = 0; ct < 4; ++ct) acc[rt][ct] = {0.f, 0.f, 0.f, 0.f};

  const bf16x8* BsV = (const bf16x8*)Bs;
  bf16x8* AsV = (bf16x8*)As;
  const int4* s4 = (const int4*)Bp;
  int4* d4 = (int4*)Bs;

  for (int h = 0; h < 2; ++h) {
    if (h) __syncthreads();                      // all waves done reading previous K-half

    // stage As: 128 rows x 128 k (f32 -> bf16). 2048 16B-slots; thread t does 4.
    // Consecutive lanes hit consecutive 32B chunks of the same row -> coalesced.
    #pragma unroll
    for (int j = 0; j < 4; ++j) {
      int sidx = tid + j * 512;
      int row = sidx >> 4, slot = sidx & 15;
      int grow = gx * 128 + row;
      if (grow > M - 1) grow = M - 1;            // clamp: dup rows only affect unwritten C
      const float* ap = A + (size_t)grow * 256 + h * 128 + slot * 8;
      float4 a0 = *(const float4*)ap;
      float4 a1 = *(const float4*)(ap + 4);
      bf16x8 u;
      u[0] = (short)f2bf(a0.x); u[1] = (short)f2bf(a0.y);
      u[2] = (short)f2bf(a0.z); u[3] = (short)f2bf(a0.w);
      u[4] = (short)f2bf(a1.x); u[5] = (short)f2bf(a1.y);
      u[6] = (short)f2bf(a1.z); u[7] = (short)f2bf(a1.w);
      AsV[row * 16 + (slot ^ (row & 7))] = u;    // XOR swizzle: frag reads 2-way max
    }
    // stage Bs: 32 KB = 2048 int4 (proven R7 indexing)
    #pragma unroll
    for (int j = 0; j < 4; ++j) {
      int f = tid + j * 512;
      int ct_l = f >> 8, r = f & 255;
      d4[f] = s4[y * 4096 + ct_l * 512 + h * 256 + r];
    }
    __syncthreads();

    #pragma unroll
    for (int srel = 0; srel < 4; ++srel) {
      bf16x8 afc[2];
      #pragma unroll
      for (int rt = 0; rt < 2; ++rt) {
        int row = rowbase_l + rt * 16 + col16;
        int slot = (srel * 4 + quad) ^ (row & 7);
        afc[rt] = AsV[row * 16 + slot];
      }
      #pragma unroll
      for (int ct = 0; ct < 4; ++ct) {
        bf16x8 bf = BsV[((wc * 4 + ct) * 4 + srel) * 64 + lane];
        #pragma unroll
        for (int rt = 0; rt < 2; ++rt)
          acc[rt][ct] = __builtin_amdgcn_mfma_f32_16x16x32_bf16(afc[rt], bf, acc[rt][ct], 0, 0, 0);
      }
    }
  }

  int hw = y * 2 + wc;                           // this col-wave's 64 cols = head hw
  float al_c[4], ar_c[4];
  #pragma unroll
  for (int ct = 0; ct < 4; ++ct) {
    int col = y * 128 + wc * 64 + ct * 16 + col16;
    al_c[ct] = al[col];
    ar_c[ct] = arr[col];
  }

  #pragma unroll
  for (int rt = 0; rt < 2; ++rt) {
    int row0 = gx * 128 + rowbase_l + rt * 16 + quad * 4;
    #pragma unroll
    for (int r = 0; r < 4; ++r) {
      int row = row0 + r;
      if (row < M) {
        #pragma unroll
        for (int ct = 0; ct < 4; ++ct) {
          int col = y * 128 + wc * 64 + ct * 16 + col16;
          Zb[(size_t)row * 256 + col] = f2bf(acc[rt][ct][r]);
        }
      }
      float pe = 0.f, pr = 0.f;
      #pragma unroll
      for (int ct = 0; ct < 4; ++ct) {
        float zv = acc[rt][ct][r];
        pe += zv * al_c[ct];
        pr += zv * ar_c[ct];
      }
      pe += __shfl_xor(pe, 1); pr += __shfl_xor(pr, 1);
      pe += __shfl_xor(pe, 2); pr += __shfl_xor(pr, 2);
      pe += __shfl_xor(pe, 4); pr += __shfl_xor(pr, 4);
      pe += __shfl_xor(pe, 8); pr += __shfl_xor(pr, 8);
      if (col16 == 0 && row < M) {
        el[(size_t)row * 4 + hw] = pe;
        er[(size_t)row * 4 + hw] = pr;
      }
    }
  }
}

// ============================ layer-1 GEMM (proven R9) ============================

__global__ __launch_bounds__(256) void gemm1_mfma_kernel(
    const unsigned short* __restrict__ Ab, const unsigned short* __restrict__ Bp,
    unsigned short* __restrict__ Zb,
    const float* __restrict__ al, const float* __restrict__ arr,
    float* __restrict__ el, float* __restrict__ er, int M) {
  int wid = threadIdx.x >> 6, lane = threadIdx.x & 63;
  int quad = lane >> 4, col16 = lane & 15;
  int m = blockIdx.x * 64 + wid * 16 + col16;

  f32x4 acc[3];
  #pragma unroll
  for (int t = 0; t < 3; ++t) acc[t] = {0.f, 0.f, 0.f, 0.f};

  const bf16x8* BpV = (const bf16x8*)Bp;

  for (int s = 0; s < 8; ++s) {
    bf16x8 af;
    if (m < M) {
      af = *(const bf16x8*)(Ab + (size_t)m * 256 + s * 32 + quad * 8);
    } else {
      #pragma unroll
      for (int j = 0; j < 8; ++j) af[j] = 0;
    }
    #pragma unroll
    for (int t = 0; t < 3; ++t) {
      bf16x8 bf = BpV[(t * 8 + s) * 64 + lane];
      acc[t] = __builtin_amdgcn_mfma_f32_16x16x32_bf16(af, bf, acc[t], 0, 0, 0);
    }
  }

  float al_c[3], ar_c[3];
  #pragma unroll
  for (int t = 0; t < 3; ++t) {
    int col = t * 16 + col16;
    al_c[t] = (col < 40) ? al[col] : 0.f;
    ar_c[t] = (col < 40) ? arr[col] : 0.f;
  }

  int row0 = blockIdx.x * 64 + wid * 16 + quad * 4;
  #pragma unroll
  for (int r = 0; r < 4; ++r) {
    int row = row0 + r;
    if (row < M) {
      #pragma unroll
      for (int t = 0; t < 3; ++t) {
        int col = t * 16 + col16;
        if (col < 40) Zb[(size_t)row * 40 + col] = f2bf(acc[t][r]);
      }
    }
    float pe = 0.f, pr = 0.f;
    #pragma unroll
    for (int t = 0; t < 3; ++t) {
      pe += acc[t][r] * al_c[t];
      pr += acc[t][r] * ar_c[t];
    }
    pe += __shfl_xor(pe, 1); pr += __shfl_xor(pr, 1);
    pe += __shfl_xor(pe, 2); pr += __shfl_xor(pr, 2);
    pe += __shfl_xor(pe, 4); pr += __shfl_xor(pr, 4);
    pe += __shfl_xor(pe, 8); pr += __shfl_xor(pr, 8);
    if (col16 == 0 && row < M) {
      el[row] = pe;
      er[row] = pr;
    }
  }
}

// ============================ layer-0 aggregation (R6 form) ============================

__global__ __launch_bounds__(256) void agg0_kernel(
    const int* __restrict__ offs, const int* __restrict__ ssrc,
    const float* __restrict__ el, const float* __restrict__ er,
    const unsigned short* __restrict__ zb, const float* __restrict__ bias,
    unsigned short* __restrict__ outb, int n) {
  __shared__ float sW[4][16][4];
  __shared__ int   sS[4][16];
  int wid  = threadIdx.x >> 6;
  int lane = threadIdx.x & 63;
  int node = blockIdx.x * 4 + wid;
  if (node >= n) return;
  int c = lane & 3, eoff = lane >> 2;
  int half = lane >> 5, colg = lane & 31, h2 = colg >> 3;
  int s0 = offs[node], s1 = offs[node + 1];
  float er_c = er[node * 4 + c];
  const unsigned short* zcol = zb + (colg << 3);

  float ssum = 0.f;
  float acc[8] = {0.f, 0.f, 0.f, 0.f, 0.f, 0.f, 0.f, 0.f};
  for (int base = s0; base < s1; base += 16) {
    int cnt = min(16, s1 - base);
    if (eoff < cnt) {
      int esrc = ssrc[base + eoff];
      float v = el[esrc * 4 + c] + er_c;
      v = v > 0.f ? v : 0.2f * v;              // leaky_relu(0.2)
      sW[wid][eoff][c] = expf(v);              // no max-shift (scores O(+-10))
      if (c == 0) sS[wid][eoff] = esrc;
    }
    for (int j = 0; j < cnt; j += 8) {
      float w[4];
      bf16x8 zu[4];
      #pragma unroll
      for (int u = 0; u < 4; ++u) {
        int jj = j + 2 * u + half;
        if (jj < cnt) {
          w[u] = sW[wid][jj][h2];
          int sn = sS[wid][jj];
          zu[u] = *(const bf16x8*)(zcol + (size_t)sn * 256);
        } else {
          w[u] = 0.f;
          #pragma unroll
          for (int i = 0; i < 8; ++i) zu[u][i] = 0;
        }
      }
      #pragma unroll
      for (int u = 0; u < 4; ++u) {
        ssum += w[u];
        #pragma unroll
        for (int i = 0; i < 8; ++i)
          acc[i] += w[u] * bf2f((unsigned short)zu[u][i]);
      }
    }
  }

  ssum += __shfl_xor(ssum, 32);
  #pragma unroll
  for (int i = 0; i < 8; ++i) acc[i] += __shfl_xor(acc[i], 32);

  float inv = (s1 > s0) ? 1.f / ssum : 0.f;    // deg==0 -> out = bias
  if (half == 0) {
    const float4 b0v = *(const float4*)(bias + (colg << 3));
    const float4 b1v = *(const float4*)(bias + (colg << 3) + 4);
    float bb[8] = {b0v.x, b0v.y, b0v.z, b0v.w, b1v.x, b1v.y, b1v.z, b1v.w};
    bf16x8 u;
    #pragma unroll
    for (int i = 0; i < 8; ++i) {
      float o = acc[i] * inv + bb[i];
      o = o > 0.f ? o : expm1f(o);             // ELU
      u[i] = (short)f2bf(o);
    }
    *(bf16x8*)(outb + (size_t)node * 256 + (colg << 3)) = u;
  }
}

// ============================ layer-1 aggregation (proven R12) ============================

__global__ __launch_bounds__(256) void agg1_kernel(
    const int* __restrict__ offs, const int* __restrict__ ssrc,
    const float* __restrict__ el, const float* __restrict__ er,
    const unsigned short* __restrict__ zb, const float* __restrict__ bias,
    float* __restrict__ out, int n) {
  __shared__ float sW[4][64];
  __shared__ int   sS[4][64];
  int wid  = threadIdx.x >> 6;
  int lane = threadIdx.x & 63;
  int node = blockIdx.x * 4 + wid;
  if (node >= n) return;
  int half = lane >> 5, d = lane & 31;
  int s0 = offs[node], s1 = offs[node + 1];
  float ern = er[node];

  float ssum = 0.f;
  float2 acc = make_float2(0.f, 0.f);
  for (int base = s0; base < s1; base += 64) {
    int cnt = min(64, s1 - base);
    if (lane < cnt) {
      int esrc = ssrc[base + lane];
      float v = el[esrc] + ern;
      v = v > 0.f ? v : 0.2f * v;
      sW[wid][lane] = expf(v);                 // no max-shift
      sS[wid][lane] = esrc;
    }
    for (int j = 0; j < cnt; j += 2) {
      int jj = j + half;
      float w = (jj < cnt) ? sW[wid][jj] : 0.f;
      int sn = sS[wid][(jj < cnt) ? jj : (cnt - 1)];
      ssum += w;
      if (d < 20) {
        unsigned zp = *(const unsigned*)(zb + (size_t)sn * 40 + (d << 1));
        acc.x += w * bf2f((unsigned short)(zp & 0xffffu));
        acc.y += w * bf2f((unsigned short)(zp >> 16));
      }
    }
  }

  ssum  += __shfl_xor(ssum, 32);
  acc.x += __shfl_xor(acc.x, 32);
  acc.y += __shfl_xor(acc.y, 32);

  float inv = (s1 > s0) ? 1.f / ssum : 0.f;
  if (half == 0 && d < 20) {
    float2 o;
    o.x = acc.x * inv + bias[(d << 1) + 0];
    o.y = acc.y * inv + bias[(d << 1) + 1];
    *(float2*)(out + (size_t)node * 40 + (d << 1)) = o;
  }
}

// ============================ launch ============================

extern "C" void kernel_launch(void* const* d_in, const int* in_sizes, int n_in,
                              void* d_out, int out_size, void* d_ws, size_t ws_size,
                              hipStream_t stream) {
  const float* x   = (const float*)d_in[0];
  const int*   src = (const int*)d_in[1];
  const int*   dst = (const int*)d_in[2];
  const float* W0  = (const float*)d_in[3];
  const float* al0 = (const float*)d_in[4];
  const float* ar0 = (const float*)d_in[5];
  const float* b0  = (const float*)d_in[6];
  const float* W1  = (const float*)d_in[7];
  const float* al1 = (const float*)d_in[8];
  const float* ar1 = (const float*)d_in[9];
  const float* b1  = (const float*)d_in[10];
  float* out = (float*)d_out;

  const int N = in_sizes[0] / 256;   // 50000
  const int E = in_sizes[1];         // 800000
  const int NB = (N + 255) / 256;    // 196 scan blocks

  char* ws = (char*)d_ws;
  size_t off = 0;
  auto alloc = [&](size_t bytes) {
    void* p = ws + off;
    off = (off + bytes + 255) & ~(size_t)255;
    return p;
  };
  unsigned short* z0b = (unsigned short*)alloc((size_t)N * 256 * 2);
  unsigned short* h0b = (unsigned short*)alloc((size_t)N * 256 * 2);
  unsigned short* z1b = (unsigned short*)alloc((size_t)N * 40 * 2);
  unsigned short* w0p = (unsigned short*)alloc((size_t)16 * 8 * 64 * 8 * 2);
  unsigned short* w1p = (unsigned short*)alloc((size_t)3 * 8 * 64 * 8 * 2);
  float* el0  = (float*)alloc((size_t)N * 4 * 4);
  float* er0  = (float*)alloc((size_t)N * 4 * 4);
  float* el1  = (float*)alloc((size_t)N * 4);
  float* er1  = (float*)alloc((size_t)N * 4);
  int* deg    = (int*)alloc((size_t)N * 4);
  int* offs   = (int*)alloc((size_t)(N + 1) * 4);
  int* cursor = (int*)alloc((size_t)N * 4);
  int* bsum   = (int*)alloc((size_t)NB * 4);
  int* boffs  = (int*)alloc((size_t)NB * 4);
  int* ssrc   = (int*)alloc((size_t)E * 4);
  (void)off; (void)ws_size; (void)n_in; (void)out_size;

  const int nG = ((N + 127) / 128) * 2;          // 782 gemm0 blocks (128 rows x col-half)
  const int nH = (E + 255) / 256;                // 3125 hist blocks
  const int nC = 391;                            // csr blocks (512 thr, ~4 edges/thread)

  // 1. deg = 0
  hipMemsetAsync(deg, 0, (size_t)N * 4, stream);
  // 2. pack || hist (no LDS -> full occupancy)
  mega0_kernel<<<38 + nH, 256, 0, stream>>>(W0, w0p, W1, w1p, dst, deg, E);
  // 3-5. exclusive scan, 3-phase
  block_sum_kernel<<<NB, 256, 0, stream>>>(deg, bsum, N);
  scan_bsum_kernel<<<1, 1024, 0, stream>>>(bsum, boffs, offs, NB, N);
  write_offsets_kernel<<<NB, 256, 0, stream>>>(deg, boffs, offs, cursor, N);
  // 6. gemm0 || build_csr, LDS-staged coalesced A
  mega2_kernel<<<nG + nC, 512, 0, stream>>>(x, w0p, z0b, al0, ar0, el0, er0, N,
                                            src, dst, cursor, ssrc, E, nG, nC);
  // 7. layer-0 aggregation + ELU -> h0b
  agg0_kernel<<<(N + 3) / 4, 256, 0, stream>>>(offs, ssrc, el0, er0, z0b, b0, h0b, N);
  // 8. layer-1 GEMM + fused el/er
  gemm1_mfma_kernel<<<(N + 63) / 64, 256, 0, stream>>>(h0b, w1p, z1b, al1, ar1, el1, er1, N);
  // 9. layer-1 aggregation -> out
  agg1_kernel<<<(N + 3) / 4, 256, 0, stream>>>(offs, ssrc, el1, er1, z1b, b1, out, N);
}

// Round 10
// 307.575 us; speedup vs baseline: 1.1298x; 1.0220x over previous
//
#include <hip/hip_runtime.h>
#include <math.h>

using bf16x8 = __attribute__((ext_vector_type(8))) short;
using f32x4  = __attribute__((ext_vector_type(4))) float;

// ---- bf16 helpers ----
__device__ __forceinline__ unsigned short f2bf(float v) {          // RNE pack
  unsigned int b = __float_as_uint(v);
  unsigned int r = (b + 0x7fffu + ((b >> 16) & 1u)) >> 16;
  return (unsigned short)r;
}
__device__ __forceinline__ float bf2f(unsigned short u) {
  return __uint_as_float(((unsigned int)u) << 16);
}

// ============ mega0: pack (blocks 0..37) || hist+slot (blocks 38..) ============
// hist now RECORDS the atomic's return value: slot[e] = rank of edge e within its dst
// segment. This makes the later CSR scatter atomic-free (p = offs[dst] + slot).

__global__ void mega0_kernel(const float* __restrict__ W0f, unsigned short* __restrict__ Bp0,
                             const float* __restrict__ W1f, unsigned short* __restrict__ Bp1,
                             const int* __restrict__ dst, int* __restrict__ deg,
                             int* __restrict__ slot, int E) {
  int bx = blockIdx.x;
  if (bx >= 38) {                                // ---- hist + slot capture ----
    int t = (bx - 38) * 256 + threadIdx.x;
    if (t < E) slot[t] = atomicAdd(&deg[dst[t]], 1);
    return;
  }
  int idx = bx * 256 + threadIdx.x;
  if (idx < 8192) {
    int lane = idx & 63, s = (idx >> 6) & 7, t = idx >> 9;
    int n = t * 16 + (lane & 15), quad = lane >> 4;
    unsigned short* o = Bp0 + (size_t)idx * 8;
    #pragma unroll
    for (int j = 0; j < 8; ++j) {
      int k = s * 32 + quad * 8 + j;
      o[j] = f2bf(W0f[(size_t)k * 256 + n]);
    }
  } else if (idx < 8192 + 1536) {
    int i1 = idx - 8192;
    int lane = i1 & 63, s = (i1 >> 6) & 7, t = i1 >> 9;
    int n = t * 16 + (lane & 15), quad = lane >> 4;
    unsigned short* o = Bp1 + (size_t)i1 * 8;
    #pragma unroll
    for (int j = 0; j < 8; ++j) {
      int k = s * 32 + quad * 8 + j;
      o[j] = (n < 40) ? f2bf(W1f[(size_t)k * 40 + n]) : 0;
    }
  }
}

// ============================ 3-phase parallel scan (proven R5-R16) ============================

__global__ void block_sum_kernel(const int* __restrict__ deg, int* __restrict__ bsum, int n) {
  __shared__ int red[4];
  int t = threadIdx.x, i = blockIdx.x * 256 + t;
  int v = (i < n) ? deg[i] : 0;
  #pragma unroll
  for (int off = 32; off; off >>= 1) v += __shfl_xor(v, off);
  if ((t & 63) == 0) red[t >> 6] = v;
  __syncthreads();
  if (t == 0) bsum[blockIdx.x] = red[0] + red[1] + red[2] + red[3];
}

__global__ void scan_bsum_kernel(const int* __restrict__ bsum, int* __restrict__ boffs,
                                 int* __restrict__ offsets, int nb, int n) {
  __shared__ int tmp[1024];
  int t = threadIdx.x;
  int v = (t < nb) ? bsum[t] : 0;
  tmp[t] = v;
  __syncthreads();
  #pragma unroll
  for (int off = 1; off < 1024; off <<= 1) {
    int add = (t >= off) ? tmp[t - off] : 0;
    __syncthreads();
    tmp[t] += add;
    __syncthreads();
  }
  if (t < nb) boffs[t] = tmp[t] - v;
  if (t == 1023) offsets[n] = tmp[1023];
}

__global__ void write_offsets_kernel(const int* __restrict__ deg, const int* __restrict__ boffs,
                                     int* __restrict__ offsets, int n) {
  __shared__ int tmp[256];
  int t = threadIdx.x, i = blockIdx.x * 256 + t;
  int v = (i < n) ? deg[i] : 0;
  tmp[t] = v;
  __syncthreads();
  #pragma unroll
  for (int off = 1; off < 256; off <<= 1) {
    int add = (t >= off) ? tmp[t - off] : 0;
    __syncthreads();
    tmp[t] += add;
    __syncthreads();
  }
  if (i < n) offsets[i] = boffs[blockIdx.x] + tmp[t] - v;
}

// ============================ mega2: R0 gemm (proven 70.5us) || atomic-free csr ============================
// gemm part: byte-exact R0 structure (256r x 128c half, 64 KB Bs, direct A loads, 4x4 acc).
// csr part: p = offs[dst[e]] + slot[e]  -- NO atomic round-trip; 3 independent loads + 1
// store per edge, fully pipelined (the 800K-atomic chain was the csr half's floor).

__global__ __launch_bounds__(512) void mega2_kernel(
    const float* __restrict__ A, const unsigned short* __restrict__ Bp,
    unsigned short* __restrict__ Zb,
    const float* __restrict__ al, const float* __restrict__ arr,
    float* __restrict__ el, float* __restrict__ er, int M,
    const int* __restrict__ src, const int* __restrict__ dst,
    const int* __restrict__ offs, const int* __restrict__ slot,
    int* __restrict__ ssrc, int E, int nG, int nC) {
  __shared__ unsigned short Bs[32768];           // 64 KB: this col-half of packed W0
  int bx = blockIdx.x;
  int tid = threadIdx.x;

  if (bx >= nG) {                                // ---- build_csr part (atomic-free) ----
    int stride = nC * 512;
    for (int e = (bx - nG) * 512 + tid; e < E; e += stride) {
      int p = offs[dst[e]] + slot[e];
      ssrc[p] = src[e];
    }
    return;
  }

  // ---- gemm0 part (exact R0) ----
  int gx = bx >> 1, y = bx & 1;
  {                                              // stage 64 KB = 4096 int4, 512 thr x 8
    const int4* s4 = (const int4*)(Bp + (size_t)y * 32768);
    int4* d4 = (int4*)Bs;
    #pragma unroll
    for (int i = 0; i < 8; ++i) d4[tid + i * 512] = s4[tid + i * 512];
  }
  __syncthreads();

  int wid = tid >> 6, lane = tid & 63;
  int quad = lane >> 4, col16 = lane & 15;
  int wr = wid >> 1, wc = wid & 1;               // 4 row-waves x 2 col-waves
  int rowbase = gx * 256 + wr * 64;

  // clamped row pointers (branch-free A loads; clamped rows only affect unwritten C-rows)
  const float* aptr[4];
  #pragma unroll
  for (int rt = 0; rt < 4; ++rt) {
    int m = rowbase + rt * 16 + col16;
    if (m > M - 1) m = M - 1;
    aptr[rt] = A + (size_t)m * 256 + quad * 8;
  }

  f32x4 acc[4][4];
  #pragma unroll
  for (int rt = 0; rt < 4; ++rt)
    #pragma unroll
    for (int ct = 0; ct < 4; ++ct) acc[rt][ct] = {0.f, 0.f, 0.f, 0.f};

  const bf16x8* BsV = (const bf16x8*)Bs;

  auto loadA = [&](bf16x8* fr, int s) {
    #pragma unroll
    for (int rt = 0; rt < 4; ++rt) {
      const float* ap = aptr[rt] + s * 32;
      float4 a0 = *(const float4*)ap;
      float4 a1 = *(const float4*)(ap + 4);
      fr[rt][0] = (short)f2bf(a0.x); fr[rt][1] = (short)f2bf(a0.y);
      fr[rt][2] = (short)f2bf(a0.z); fr[rt][3] = (short)f2bf(a0.w);
      fr[rt][4] = (short)f2bf(a1.x); fr[rt][5] = (short)f2bf(a1.y);
      fr[rt][6] = (short)f2bf(a1.z); fr[rt][7] = (short)f2bf(a1.w);
    }
  };

  bf16x8 afc[4];
  loadA(afc, 0);
  for (int s = 0; s < 8; ++s) {
    bf16x8 afn[4];
    if (s < 7) loadA(afn, s + 1);                // prefetch next k-step
    #pragma unroll
    for (int ct = 0; ct < 4; ++ct) {
      bf16x8 bf = BsV[((wc * 4 + ct) * 8 + s) * 64 + lane];
      #pragma unroll
      for (int rt = 0; rt < 4; ++rt)
        acc[rt][ct] = __builtin_amdgcn_mfma_f32_16x16x32_bf16(afc[rt], bf, acc[rt][ct], 0, 0, 0);
    }
    if (s < 7) {
      #pragma unroll
      for (int rt = 0; rt < 4; ++rt) afc[rt] = afn[rt];
    }
  }

  int hw = y * 2 + wc;
  float al_c[4], ar_c[4];
  #pragma unroll
  for (int ct = 0; ct < 4; ++ct) {
    int col = y * 128 + (wc * 4 + ct) * 16 + col16;
    al_c[ct] = al[col];
    ar_c[ct] = arr[col];
  }

  #pragma unroll
  for (int rt = 0; rt < 4; ++rt) {
    int row0 = rowbase + rt * 16 + quad * 4;
    #pragma unroll
    for (int r = 0; r < 4; ++r) {
      int row = row0 + r;
      if (row < M) {
        #pragma unroll
        for (int ct = 0; ct < 4; ++ct) {
          int col = y * 128 + (wc * 4 + ct) * 16 + col16;
          Zb[(size_t)row * 256 + col] = f2bf(acc[rt][ct][r]);
        }
      }
      float pe = 0.f, pr = 0.f;
      #pragma unroll
      for (int ct = 0; ct < 4; ++ct) {
        float zv = acc[rt][ct][r];
        pe += zv * al_c[ct];
        pr += zv * ar_c[ct];
      }
      pe += __shfl_xor(pe, 1); pr += __shfl_xor(pr, 1);
      pe += __shfl_xor(pe, 2); pr += __shfl_xor(pr, 2);
      pe += __shfl_xor(pe, 4); pr += __shfl_xor(pr, 4);
      pe += __shfl_xor(pe, 8); pr += __shfl_xor(pr, 8);
      if (col16 == 0 && row < M) {
        el[(size_t)row * 4 + hw] = pe;
        er[(size_t)row * 4 + hw] = pr;
      }
    }
  }
}

// ============================ layer-1 GEMM (proven R9) ============================

__global__ __launch_bounds__(256) void gemm1_mfma_kernel(
    const unsigned short* __restrict__ Ab, const unsigned short* __restrict__ Bp,
    unsigned short* __restrict__ Zb,
    const float* __restrict__ al, const float* __restrict__ arr,
    float* __restrict__ el, float* __restrict__ er, int M) {
  int wid = threadIdx.x >> 6, lane = threadIdx.x & 63;
  int quad = lane >> 4, col16 = lane & 15;
  int m = blockIdx.x * 64 + wid * 16 + col16;

  f32x4 acc[3];
  #pragma unroll
  for (int t = 0; t < 3; ++t) acc[t] = {0.f, 0.f, 0.f, 0.f};

  const bf16x8* BpV = (const bf16x8*)Bp;

  for (int s = 0; s < 8; ++s) {
    bf16x8 af;
    if (m < M) {
      af = *(const bf16x8*)(Ab + (size_t)m * 256 + s * 32 + quad * 8);
    } else {
      #pragma unroll
      for (int j = 0; j < 8; ++j) af[j] = 0;
    }
    #pragma unroll
    for (int t = 0; t < 3; ++t) {
      bf16x8 bf = BpV[(t * 8 + s) * 64 + lane];
      acc[t] = __builtin_amdgcn_mfma_f32_16x16x32_bf16(af, bf, acc[t], 0, 0, 0);
    }
  }

  float al_c[3], ar_c[3];
  #pragma unroll
  for (int t = 0; t < 3; ++t) {
    int col = t * 16 + col16;
    al_c[t] = (col < 40) ? al[col] : 0.f;
    ar_c[t] = (col < 40) ? arr[col] : 0.f;
  }

  int row0 = blockIdx.x * 64 + wid * 16 + quad * 4;
  #pragma unroll
  for (int r = 0; r < 4; ++r) {
    int row = row0 + r;
    if (row < M) {
      #pragma unroll
      for (int t = 0; t < 3; ++t) {
        int col = t * 16 + col16;
        if (col < 40) Zb[(size_t)row * 40 + col] = f2bf(acc[t][r]);
      }
    }
    float pe = 0.f, pr = 0.f;
    #pragma unroll
    for (int t = 0; t < 3; ++t) {
      pe += acc[t][r] * al_c[t];
      pr += acc[t][r] * ar_c[t];
    }
    pe += __shfl_xor(pe, 1); pr += __shfl_xor(pr, 1);
    pe += __shfl_xor(pe, 2); pr += __shfl_xor(pr, 2);
    pe += __shfl_xor(pe, 4); pr += __shfl_xor(pr, 4);
    pe += __shfl_xor(pe, 8); pr += __shfl_xor(pr, 8);
    if (col16 == 0 && row < M) {
      el[row] = pe;
      er[row] = pr;
    }
  }
}

// ============================ layer-0 aggregation (R6 form, at memory roofline) ============================

__global__ __launch_bounds__(256) void agg0_kernel(
    const int* __restrict__ offs, const int* __restrict__ ssrc,
    const float* __restrict__ el, const float* __restrict__ er,
    const unsigned short* __restrict__ zb, const float* __restrict__ bias,
    unsigned short* __restrict__ outb, int n) {
  __shared__ float sW[4][16][4];
  __shared__ int   sS[4][16];
  int wid  = threadIdx.x >> 6;
  int lane = threadIdx.x & 63;
  int node = blockIdx.x * 4 + wid;
  if (node >= n) return;
  int c = lane & 3, eoff = lane >> 2;
  int half = lane >> 5, colg = lane & 31, h2 = colg >> 3;
  int s0 = offs[node], s1 = offs[node + 1];
  float er_c = er[node * 4 + c];
  const unsigned short* zcol = zb + (colg << 3);

  float ssum = 0.f;
  float acc[8] = {0.f, 0.f, 0.f, 0.f, 0.f, 0.f, 0.f, 0.f};
  for (int base = s0; base < s1; base += 16) {
    int cnt = min(16, s1 - base);
    if (eoff < cnt) {
      int esrc = ssrc[base + eoff];
      float v = el[esrc * 4 + c] + er_c;
      v = v > 0.f ? v : 0.2f * v;              // leaky_relu(0.2)
      sW[wid][eoff][c] = expf(v);              // no max-shift (scores O(+-10))
      if (c == 0) sS[wid][eoff] = esrc;
    }
    for (int j = 0; j < cnt; j += 8) {
      float w[4];
      bf16x8 zu[4];
      #pragma unroll
      for (int u = 0; u < 4; ++u) {
        int jj = j + 2 * u + half;
        if (jj < cnt) {
          w[u] = sW[wid][jj][h2];
          int sn = sS[wid][jj];
          zu[u] = *(const bf16x8*)(zcol + (size_t)sn * 256);
        } else {
          w[u] = 0.f;
          #pragma unroll
          for (int i = 0; i < 8; ++i) zu[u][i] = 0;
        }
      }
      #pragma unroll
      for (int u = 0; u < 4; ++u) {
        ssum += w[u];
        #pragma unroll
        for (int i = 0; i < 8; ++i)
          acc[i] += w[u] * bf2f((unsigned short)zu[u][i]);
      }
    }
  }

  ssum += __shfl_xor(ssum, 32);
  #pragma unroll
  for (int i = 0; i < 8; ++i) acc[i] += __shfl_xor(acc[i], 32);

  float inv = (s1 > s0) ? 1.f / ssum : 0.f;    // deg==0 -> out = bias
  if (half == 0) {
    const float4 b0v = *(const float4*)(bias + (colg << 3));
    const float4 b1v = *(const float4*)(bias + (colg << 3) + 4);
    float bb[8] = {b0v.x, b0v.y, b0v.z, b0v.w, b1v.x, b1v.y, b1v.z, b1v.w};
    bf16x8 u;
    #pragma unroll
    for (int i = 0; i < 8; ++i) {
      float o = acc[i] * inv + bb[i];
      o = o > 0.f ? o : expm1f(o);             // ELU
      u[i] = (short)f2bf(o);
    }
    *(bf16x8*)(outb + (size_t)node * 256 + (colg << 3)) = u;
  }
}

// ============================ layer-1 aggregation (proven R12) ============================

__global__ __launch_bounds__(256) void agg1_kernel(
    const int* __restrict__ offs, const int* __restrict__ ssrc,
    const float* __restrict__ el, const float* __restrict__ er,
    const unsigned short* __restrict__ zb, const float* __restrict__ bias,
    float* __restrict__ out, int n) {
  __shared__ float sW[4][64];
  __shared__ int   sS[4][64];
  int wid  = threadIdx.x >> 6;
  int lane = threadIdx.x & 63;
  int node = blockIdx.x * 4 + wid;
  if (node >= n) return;
  int half = lane >> 5, d = lane & 31;
  int s0 = offs[node], s1 = offs[node + 1];
  float ern = er[node];

  float ssum = 0.f;
  float2 acc = make_float2(0.f, 0.f);
  for (int base = s0; base < s1; base += 64) {
    int cnt = min(64, s1 - base);
    if (lane < cnt) {
      int esrc = ssrc[base + lane];
      float v = el[esrc] + ern;
      v = v > 0.f ? v : 0.2f * v;
      sW[wid][lane] = expf(v);                 // no max-shift
      sS[wid][lane] = esrc;
    }
    for (int j = 0; j < cnt; j += 2) {
      int jj = j + half;
      float w = (jj < cnt) ? sW[wid][jj] : 0.f;
      int sn = sS[wid][(jj < cnt) ? jj : (cnt - 1)];
      ssum += w;
      if (d < 20) {
        unsigned zp = *(const unsigned*)(zb + (size_t)sn * 40 + (d << 1));
        acc.x += w * bf2f((unsigned short)(zp & 0xffffu));
        acc.y += w * bf2f((unsigned short)(zp >> 16));
      }
    }
  }

  ssum  += __shfl_xor(ssum, 32);
  acc.x += __shfl_xor(acc.x, 32);
  acc.y += __shfl_xor(acc.y, 32);

  float inv = (s1 > s0) ? 1.f / ssum : 0.f;
  if (half == 0 && d < 20) {
    float2 o;
    o.x = acc.x * inv + bias[(d << 1) + 0];
    o.y = acc.y * inv + bias[(d << 1) + 1];
    *(float2*)(out + (size_t)node * 40 + (d << 1)) = o;
  }
}

// ============================ launch ============================

extern "C" void kernel_launch(void* const* d_in, const int* in_sizes, int n_in,
                              void* d_out, int out_size, void* d_ws, size_t ws_size,
                              hipStream_t stream) {
  const float* x   = (const float*)d_in[0];
  const int*   src = (const int*)d_in[1];
  const int*   dst = (const int*)d_in[2];
  const float* W0  = (const float*)d_in[3];
  const float* al0 = (const float*)d_in[4];
  const float* ar0 = (const float*)d_in[5];
  const float* b0  = (const float*)d_in[6];
  const float* W1  = (const float*)d_in[7];
  const float* al1 = (const float*)d_in[8];
  const float* ar1 = (const float*)d_in[9];
  const float* b1  = (const float*)d_in[10];
  float* out = (float*)d_out;

  const int N = in_sizes[0] / 256;   // 50000
  const int E = in_sizes[1];         // 800000
  const int NB = (N + 255) / 256;    // 196 scan blocks

  char* ws = (char*)d_ws;
  size_t off = 0;
  auto alloc = [&](size_t bytes) {
    void* p = ws + off;
    off = (off + bytes + 255) & ~(size_t)255;
    return p;
  };
  unsigned short* z0b = (unsigned short*)alloc((size_t)N * 256 * 2);
  unsigned short* h0b = (unsigned short*)alloc((size_t)N * 256 * 2);
  unsigned short* z1b = (unsigned short*)alloc((size_t)N * 40 * 2);
  unsigned short* w0p = (unsigned short*)alloc((size_t)16 * 8 * 64 * 8 * 2);
  unsigned short* w1p = (unsigned short*)alloc((size_t)3 * 8 * 64 * 8 * 2);
  float* el0  = (float*)alloc((size_t)N * 4 * 4);
  float* er0  = (float*)alloc((size_t)N * 4 * 4);
  float* el1  = (float*)alloc((size_t)N * 4);
  float* er1  = (float*)alloc((size_t)N * 4);
  int* deg    = (int*)alloc((size_t)N * 4);
  int* offs   = (int*)alloc((size_t)(N + 1) * 4);
  int* slot   = (int*)alloc((size_t)E * 4);
  int* bsum   = (int*)alloc((size_t)NB * 4);
  int* boffs  = (int*)alloc((size_t)NB * 4);
  int* ssrc   = (int*)alloc((size_t)E * 4);
  (void)off; (void)ws_size; (void)n_in; (void)out_size;

  const int nG = ((N + 255) / 256) * 2;          // 392 gemm0 blocks (256 rows x col-half)
  const int nH = (E + 255) / 256;                // 3125 hist blocks
  const int nC = 391;                            // csr blocks (512 thr, ~4 edges/thread)

  // 1. deg = 0
  hipMemsetAsync(deg, 0, (size_t)N * 4, stream);
  // 2. pack || hist+slot (no LDS -> full occupancy)
  mega0_kernel<<<38 + nH, 256, 0, stream>>>(W0, w0p, W1, w1p, dst, deg, slot, E);
  // 3-5. exclusive scan, 3-phase
  block_sum_kernel<<<NB, 256, 0, stream>>>(deg, bsum, N);
  scan_bsum_kernel<<<1, 1024, 0, stream>>>(bsum, boffs, offs, NB, N);
  write_offsets_kernel<<<NB, 256, 0, stream>>>(deg, boffs, offs, N);
  // 6. gemm0 (exact R0) || build_csr (atomic-free: offs + slot)
  mega2_kernel<<<nG + nC, 512, 0, stream>>>(x, w0p, z0b, al0, ar0, el0, er0, N,
                                            src, dst, offs, slot, ssrc, E, nG, nC);
  // 7. layer-0 aggregation + ELU -> h0b
  agg0_kernel<<<(N + 3) / 4, 256, 0, stream>>>(offs, ssrc, el0, er0, z0b, b0, h0b, N);
  // 8. layer-1 GEMM + fused el/er
  gemm1_mfma_kernel<<<(N + 63) / 64, 256, 0, stream>>>(h0b, w1p, z1b, al1, ar1, el1, er1, N);
  // 9. layer-1 aggregation -> out
  agg1_kernel<<<(N + 3) / 4, 256, 0, stream>>>(offs, ssrc, el1, er1, z1b, b1, out, N);
}

// Round 12
// 306.744 us; speedup vs baseline: 1.1328x; 1.0027x over previous
//
#include <hip/hip_runtime.h>
#include <math.h>

using bf16x8 = __attribute__((ext_vector_type(8))) short;
using f32x4  = __attribute__((ext_vector_type(4))) float;

// ---- bf16 helpers ----
__device__ __forceinline__ unsigned short f2bf(float v) {          // RNE pack
  unsigned int b = __float_as_uint(v);
  unsigned int r = (b + 0x7fffu + ((b >> 16) & 1u)) >> 16;
  return (unsigned short)r;
}
__device__ __forceinline__ float bf2f(unsigned short u) {
  return __uint_as_float(((unsigned int)u) << 16);
}

// ============ mega0: pack (blocks 0..37) || hist+slot (blocks 38..) (proven R10) ============
// hist RECORDS the atomic's return value: slot[e] = rank of edge e within its dst segment,
// making the later CSR scatter atomic-free (p = offs[dst] + slot).

__global__ void mega0_kernel(const float* __restrict__ W0f, unsigned short* __restrict__ Bp0,
                             const float* __restrict__ W1f, unsigned short* __restrict__ Bp1,
                             const int* __restrict__ dst, int* __restrict__ deg,
                             int* __restrict__ slot, int E) {
  int bx = blockIdx.x;
  if (bx >= 38) {                                // ---- hist + slot capture ----
    int t = (bx - 38) * 256 + threadIdx.x;
    if (t < E) slot[t] = atomicAdd(&deg[dst[t]], 1);
    return;
  }
  int idx = bx * 256 + threadIdx.x;
  if (idx < 8192) {
    int lane = idx & 63, s = (idx >> 6) & 7, t = idx >> 9;
    int n = t * 16 + (lane & 15), quad = lane >> 4;
    unsigned short* o = Bp0 + (size_t)idx * 8;
    #pragma unroll
    for (int j = 0; j < 8; ++j) {
      int k = s * 32 + quad * 8 + j;
      o[j] = f2bf(W0f[(size_t)k * 256 + n]);
    }
  } else if (idx < 8192 + 1536) {
    int i1 = idx - 8192;
    int lane = i1 & 63, s = (i1 >> 6) & 7, t = i1 >> 9;
    int n = t * 16 + (lane & 15), quad = lane >> 4;
    unsigned short* o = Bp1 + (size_t)i1 * 8;
    #pragma unroll
    for (int j = 0; j < 8; ++j) {
      int k = s * 32 + quad * 8 + j;
      o[j] = (n < 40) ? f2bf(W1f[(size_t)k * 40 + n]) : 0;
    }
  }
}

// ============================ 3-phase parallel scan (proven R5-R16) ============================

__global__ void block_sum_kernel(const int* __restrict__ deg, int* __restrict__ bsum, int n) {
  __shared__ int red[4];
  int t = threadIdx.x, i = blockIdx.x * 256 + t;
  int v = (i < n) ? deg[i] : 0;
  #pragma unroll
  for (int off = 32; off; off >>= 1) v += __shfl_xor(v, off);
  if ((t & 63) == 0) red[t >> 6] = v;
  __syncthreads();
  if (t == 0) bsum[blockIdx.x] = red[0] + red[1] + red[2] + red[3];
}

__global__ void scan_bsum_kernel(const int* __restrict__ bsum, int* __restrict__ boffs,
                                 int* __restrict__ offsets, int nb, int n) {
  __shared__ int tmp[1024];
  int t = threadIdx.x;
  int v = (t < nb) ? bsum[t] : 0;
  tmp[t] = v;
  __syncthreads();
  #pragma unroll
  for (int off = 1; off < 1024; off <<= 1) {
    int add = (t >= off) ? tmp[t - off] : 0;
    __syncthreads();
    tmp[t] += add;
    __syncthreads();
  }
  if (t < nb) boffs[t] = tmp[t] - v;
  if (t == 1023) offsets[n] = tmp[1023];
}

__global__ void write_offsets_kernel(const int* __restrict__ deg, const int* __restrict__ boffs,
                                     int* __restrict__ offsets, int n) {
  __shared__ int tmp[256];
  int t = threadIdx.x, i = blockIdx.x * 256 + t;
  int v = (i < n) ? deg[i] : 0;
  tmp[t] = v;
  __syncthreads();
  #pragma unroll
  for (int off = 1; off < 256; off <<= 1) {
    int add = (t >= off) ? tmp[t - off] : 0;
    __syncthreads();
    tmp[t] += add;
    __syncthreads();
  }
  if (i < n) offsets[i] = boffs[blockIdx.x] + tmp[t] - v;
}

// ============================ mega2 v8b: B direct from L2 (no LDS), atomic-free csr ============================
// All 392 gemm blocks read the SAME 128 KB packed W0 -> permanently L2-hot; the fragment
// read (16B/lane over a contiguous 1 KB) is coalesced. No LDS, no barriers; gemm + csr
// waves mix freely. A loads, acc, epilogue byte-identical to the proven R0 form.
// R11 bug fixed: col-half stride is 4096 frags (8 tiles x 512), not 2048.

__global__ __launch_bounds__(512) void mega2_kernel(
    const float* __restrict__ A, const unsigned short* __restrict__ Bp,
    unsigned short* __restrict__ Zb,
    const float* __restrict__ al, const float* __restrict__ arr,
    float* __restrict__ el, float* __restrict__ er, int M,
    const int* __restrict__ src, const int* __restrict__ dst,
    const int* __restrict__ offs, const int* __restrict__ slot,
    int* __restrict__ ssrc, int E, int nG, int nC) {
  int bx = blockIdx.x;
  int tid = threadIdx.x;

  if (bx >= nG) {                                // ---- build_csr part (atomic-free) ----
    int stride = nC * 512;
    for (int e = (bx - nG) * 512 + tid; e < E; e += stride) {
      int p = offs[dst[e]] + slot[e];
      ssrc[p] = src[e];
    }
    return;
  }

  // ---- gemm0 part ----
  int gx = bx >> 1, y = bx & 1;
  int wid = tid >> 6, lane = tid & 63;
  int quad = lane >> 4, col16 = lane & 15;
  int wr = wid >> 1, wc = wid & 1;               // 4 row-waves x 2 col-waves
  int rowbase = gx * 256 + wr * 64;

  // clamped row pointers (branch-free A loads; clamped rows only affect unwritten C-rows)
  const float* aptr[4];
  #pragma unroll
  for (int rt = 0; rt < 4; ++rt) {
    int m = rowbase + rt * 16 + col16;
    if (m > M - 1) m = M - 1;
    aptr[rt] = A + (size_t)m * 256 + quad * 8;
  }

  f32x4 acc[4][4];
  #pragma unroll
  for (int rt = 0; rt < 4; ++rt)
    #pragma unroll
    for (int ct = 0; ct < 4; ++ct) acc[rt][ct] = {0.f, 0.f, 0.f, 0.f};

  const bf16x8* BpV = (const bf16x8*)Bp;         // B frags straight from L1/L2-hot global

  auto loadA = [&](bf16x8* fr, int s) {
    #pragma unroll
    for (int rt = 0; rt < 4; ++rt) {
      const float* ap = aptr[rt] + s * 32;
      float4 a0 = *(const float4*)ap;
      float4 a1 = *(const float4*)(ap + 4);
      fr[rt][0] = (short)f2bf(a0.x); fr[rt][1] = (short)f2bf(a0.y);
      fr[rt][2] = (short)f2bf(a0.z); fr[rt][3] = (short)f2bf(a0.w);
      fr[rt][4] = (short)f2bf(a1.x); fr[rt][5] = (short)f2bf(a1.y);
      fr[rt][6] = (short)f2bf(a1.z); fr[rt][7] = (short)f2bf(a1.w);
    }
  };

  bf16x8 afc[4];
  loadA(afc, 0);
  for (int s = 0; s < 8; ++s) {
    bf16x8 afn[4];
    if (s < 7) loadA(afn, s + 1);                // prefetch next k-step
    #pragma unroll
    for (int ct = 0; ct < 4; ++ct) {
      bf16x8 bf = BpV[y * 4096 + ((wc * 4 + ct) * 8 + s) * 64 + lane];
      #pragma unroll
      for (int rt = 0; rt < 4; ++rt)
        acc[rt][ct] = __builtin_amdgcn_mfma_f32_16x16x32_bf16(afc[rt], bf, acc[rt][ct], 0, 0, 0);
    }
    if (s < 7) {
      #pragma unroll
      for (int rt = 0; rt < 4; ++rt) afc[rt] = afn[rt];
    }
  }

  int hw = y * 2 + wc;
  float al_c[4], ar_c[4];
  #pragma unroll
  for (int ct = 0; ct < 4; ++ct) {
    int col = y * 128 + (wc * 4 + ct) * 16 + col16;
    al_c[ct] = al[col];
    ar_c[ct] = arr[col];
  }

  #pragma unroll
  for (int rt = 0; rt < 4; ++rt) {
    int row0 = rowbase + rt * 16 + quad * 4;
    #pragma unroll
    for (int r = 0; r < 4; ++r) {
      int row = row0 + r;
      if (row < M) {
        #pragma unroll
        for (int ct = 0; ct < 4; ++ct) {
          int col = y * 128 + (wc * 4 + ct) * 16 + col16;
          Zb[(size_t)row * 256 + col] = f2bf(acc[rt][ct][r]);
        }
      }
      float pe = 0.f, pr = 0.f;
      #pragma unroll
      for (int ct = 0; ct < 4; ++ct) {
        float zv = acc[rt][ct][r];
        pe += zv * al_c[ct];
        pr += zv * ar_c[ct];
      }
      pe += __shfl_xor(pe, 1); pr += __shfl_xor(pr, 1);
      pe += __shfl_xor(pe, 2); pr += __shfl_xor(pr, 2);
      pe += __shfl_xor(pe, 4); pr += __shfl_xor(pr, 4);
      pe += __shfl_xor(pe, 8); pr += __shfl_xor(pr, 8);
      if (col16 == 0 && row < M) {
        el[(size_t)row * 4 + hw] = pe;
        er[(size_t)row * 4 + hw] = pr;
      }
    }
  }
}

// ============================ layer-1 GEMM (proven R9) ============================

__global__ __launch_bounds__(256) void gemm1_mfma_kernel(
    const unsigned short* __restrict__ Ab, const unsigned short* __restrict__ Bp,
    unsigned short* __restrict__ Zb,
    const float* __restrict__ al, const float* __restrict__ arr,
    float* __restrict__ el, float* __restrict__ er, int M) {
  int wid = threadIdx.x >> 6, lane = threadIdx.x & 63;
  int quad = lane >> 4, col16 = lane & 15;
  int m = blockIdx.x * 64 + wid * 16 + col16;

  f32x4 acc[3];
  #pragma unroll
  for (int t = 0; t < 3; ++t) acc[t] = {0.f, 0.f, 0.f, 0.f};

  const bf16x8* BpV = (const bf16x8*)Bp;

  for (int s = 0; s < 8; ++s) {
    bf16x8 af;
    if (m < M) {
      af = *(const bf16x8*)(Ab + (size_t)m * 256 + s * 32 + quad * 8);
    } else {
      #pragma unroll
      for (int j = 0; j < 8; ++j) af[j] = 0;
    }
    #pragma unroll
    for (int t = 0; t < 3; ++t) {
      bf16x8 bf = BpV[(t * 8 + s) * 64 + lane];
      acc[t] = __builtin_amdgcn_mfma_f32_16x16x32_bf16(af, bf, acc[t], 0, 0, 0);
    }
  }

  float al_c[3], ar_c[3];
  #pragma unroll
  for (int t = 0; t < 3; ++t) {
    int col = t * 16 + col16;
    al_c[t] = (col < 40) ? al[col] : 0.f;
    ar_c[t] = (col < 40) ? arr[col] : 0.f;
  }

  int row0 = blockIdx.x * 64 + wid * 16 + quad * 4;
  #pragma unroll
  for (int r = 0; r < 4; ++r) {
    int row = row0 + r;
    if (row < M) {
      #pragma unroll
      for (int t = 0; t < 3; ++t) {
        int col = t * 16 + col16;
        if (col < 40) Zb[(size_t)row * 40 + col] = f2bf(acc[t][r]);
      }
    }
    float pe = 0.f, pr = 0.f;
    #pragma unroll
    for (int t = 0; t < 3; ++t) {
      pe += acc[t][r] * al_c[t];
      pr += acc[t][r] * ar_c[t];
    }
    pe += __shfl_xor(pe, 1); pr += __shfl_xor(pr, 1);
    pe += __shfl_xor(pe, 2); pr += __shfl_xor(pr, 2);
    pe += __shfl_xor(pe, 4); pr += __shfl_xor(pr, 4);
    pe += __shfl_xor(pe, 8); pr += __shfl_xor(pr, 8);
    if (col16 == 0 && row < M) {
      el[row] = pe;
      er[row] = pr;
    }
  }
}

// ============================ layer-0 aggregation (R6 form, at memory roofline) ============================

__global__ __launch_bounds__(256) void agg0_kernel(
    const int* __restrict__ offs, const int* __restrict__ ssrc,
    const float* __restrict__ el, const float* __restrict__ er,
    const unsigned short* __restrict__ zb, const float* __restrict__ bias,
    unsigned short* __restrict__ outb, int n) {
  __shared__ float sW[4][16][4];
  __shared__ int   sS[4][16];
  int wid  = threadIdx.x >> 6;
  int lane = threadIdx.x & 63;
  int node = blockIdx.x * 4 + wid;
  if (node >= n) return;
  int c = lane & 3, eoff = lane >> 2;
  int half = lane >> 5, colg = lane & 31, h2 = colg >> 3;
  int s0 = offs[node], s1 = offs[node + 1];
  float er_c = er[node * 4 + c];
  const unsigned short* zcol = zb + (colg << 3);

  float ssum = 0.f;
  float acc[8] = {0.f, 0.f, 0.f, 0.f, 0.f, 0.f, 0.f, 0.f};
  for (int base = s0; base < s1; base += 16) {
    int cnt = min(16, s1 - base);
    if (eoff < cnt) {
      int esrc = ssrc[base + eoff];
      float v = el[esrc * 4 + c] + er_c;
      v = v > 0.f ? v : 0.2f * v;              // leaky_relu(0.2)
      sW[wid][eoff][c] = expf(v);              // no max-shift (scores O(+-10))
      if (c == 0) sS[wid][eoff] = esrc;
    }
    for (int j = 0; j < cnt; j += 8) {
      float w[4];
      bf16x8 zu[4];
      #pragma unroll
      for (int u = 0; u < 4; ++u) {
        int jj = j + 2 * u + half;
        if (jj < cnt) {
          w[u] = sW[wid][jj][h2];
          int sn = sS[wid][jj];
          zu[u] = *(const bf16x8*)(zcol + (size_t)sn * 256);
        } else {
          w[u] = 0.f;
          #pragma unroll
          for (int i = 0; i < 8; ++i) zu[u][i] = 0;
        }
      }
      #pragma unroll
      for (int u = 0; u < 4; ++u) {
        ssum += w[u];
        #pragma unroll
        for (int i = 0; i < 8; ++i)
          acc[i] += w[u] * bf2f((unsigned short)zu[u][i]);
      }
    }
  }

  ssum += __shfl_xor(ssum, 32);
  #pragma unroll
  for (int i = 0; i < 8; ++i) acc[i] += __shfl_xor(acc[i], 32);

  float inv = (s1 > s0) ? 1.f / ssum : 0.f;    // deg==0 -> out = bias
  if (half == 0) {
    const float4 b0v = *(const float4*)(bias + (colg << 3));
    const float4 b1v = *(const float4*)(bias + (colg << 3) + 4);
    float bb[8] = {b0v.x, b0v.y, b0v.z, b0v.w, b1v.x, b1v.y, b1v.z, b1v.w};
    bf16x8 u;
    #pragma unroll
    for (int i = 0; i < 8; ++i) {
      float o = acc[i] * inv + bb[i];
      o = o > 0.f ? o : expm1f(o);             // ELU
      u[i] = (short)f2bf(o);
    }
    *(bf16x8*)(outb + (size_t)node * 256 + (colg << 3)) = u;
  }
}

// ============================ layer-1 aggregation (proven R12) ============================

__global__ __launch_bounds__(256) void agg1_kernel(
    const int* __restrict__ offs, const int* __restrict__ ssrc,
    const float* __restrict__ el, const float* __restrict__ er,
    const unsigned short* __restrict__ zb, const float* __restrict__ bias,
    float* __restrict__ out, int n) {
  __shared__ float sW[4][64];
  __shared__ int   sS[4][64];
  int wid  = threadIdx.x >> 6;
  int lane = threadIdx.x & 63;
  int node = blockIdx.x * 4 + wid;
  if (node >= n) return;
  int half = lane >> 5, d = lane & 31;
  int s0 = offs[node], s1 = offs[node + 1];
  float ern = er[node];

  float ssum = 0.f;
  float2 acc = make_float2(0.f, 0.f);
  for (int base = s0; base < s1; base += 64) {
    int cnt = min(64, s1 - base);
    if (lane < cnt) {
      int esrc = ssrc[base + lane];
      float v = el[esrc] + ern;
      v = v > 0.f ? v : 0.2f * v;
      sW[wid][lane] = expf(v);                 // no max-shift
      sS[wid][lane] = esrc;
    }
    for (int j = 0; j < cnt; j += 2) {
      int jj = j + half;
      float w = (jj < cnt) ? sW[wid][jj] : 0.f;
      int sn = sS[wid][(jj < cnt) ? jj : (cnt - 1)];
      ssum += w;
      if (d < 20) {
        unsigned zp = *(const unsigned*)(zb + (size_t)sn * 40 + (d << 1));
        acc.x += w * bf2f((unsigned short)(zp & 0xffffu));
        acc.y += w * bf2f((unsigned short)(zp >> 16));
      }
    }
  }

  ssum  += __shfl_xor(ssum, 32);
  acc.x += __shfl_xor(acc.x, 32);
  acc.y += __shfl_xor(acc.y, 32);

  float inv = (s1 > s0) ? 1.f / ssum : 0.f;
  if (half == 0 && d < 20) {
    float2 o;
    o.x = acc.x * inv + bias[(d << 1) + 0];
    o.y = acc.y * inv + bias[(d << 1) + 1];
    *(float2*)(out + (size_t)node * 40 + (d << 1)) = o;
  }
}

// ============================ launch ============================

extern "C" void kernel_launch(void* const* d_in, const int* in_sizes, int n_in,
                              void* d_out, int out_size, void* d_ws, size_t ws_size,
                              hipStream_t stream) {
  const float* x   = (const float*)d_in[0];
  const int*   src = (const int*)d_in[1];
  const int*   dst = (const int*)d_in[2];
  const float* W0  = (const float*)d_in[3];
  const float* al0 = (const float*)d_in[4];
  const float* ar0 = (const float*)d_in[5];
  const float* b0  = (const float*)d_in[6];
  const float* W1  = (const float*)d_in[7];
  const float* al1 = (const float*)d_in[8];
  const float* ar1 = (const float*)d_in[9];
  const float* b1  = (const float*)d_in[10];
  float* out = (float*)d_out;

  const int N = in_sizes[0] / 256;   // 50000
  const int E = in_sizes[1];         // 800000
  const int NB = (N + 255) / 256;    // 196 scan blocks

  char* ws = (char*)d_ws;
  size_t off = 0;
  auto alloc = [&](size_t bytes) {
    void* p = ws + off;
    off = (off + bytes + 255) & ~(size_t)255;
    return p;
  };
  unsigned short* z0b = (unsigned short*)alloc((size_t)N * 256 * 2);
  unsigned short* h0b = (unsigned short*)alloc((size_t)N * 256 * 2);
  unsigned short* z1b = (unsigned short*)alloc((size_t)N * 40 * 2);
  unsigned short* w0p = (unsigned short*)alloc((size_t)16 * 8 * 64 * 8 * 2);
  unsigned short* w1p = (unsigned short*)alloc((size_t)3 * 8 * 64 * 8 * 2);
  float* el0  = (float*)alloc((size_t)N * 4 * 4);
  float* er0  = (float*)alloc((size_t)N * 4 * 4);
  float* el1  = (float*)alloc((size_t)N * 4);
  float* er1  = (float*)alloc((size_t)N * 4);
  int* deg    = (int*)alloc((size_t)N * 4);
  int* offs   = (int*)alloc((size_t)(N + 1) * 4);
  int* slot   = (int*)alloc((size_t)E * 4);
  int* bsum   = (int*)alloc((size_t)NB * 4);
  int* boffs  = (int*)alloc((size_t)NB * 4);
  int* ssrc   = (int*)alloc((size_t)E * 4);
  (void)off; (void)ws_size; (void)n_in; (void)out_size;

  const int nG = ((N + 255) / 256) * 2;          // 392 gemm0 blocks (256 rows x col-half)
  const int nH = (E + 255) / 256;                // 3125 hist blocks
  const int nC = 391;                            // csr blocks (512 thr, ~4 edges/thread)

  // 1. deg = 0
  hipMemsetAsync(deg, 0, (size_t)N * 4, stream);
  // 2. pack || hist+slot (no LDS -> full occupancy)
  mega0_kernel<<<38 + nH, 256, 0, stream>>>(W0, w0p, W1, w1p, dst, deg, slot, E);
  // 3-5. exclusive scan, 3-phase
  block_sum_kernel<<<NB, 256, 0, stream>>>(deg, bsum, N);
  scan_bsum_kernel<<<1, 1024, 0, stream>>>(bsum, boffs, offs, NB, N);
  write_offsets_kernel<<<NB, 256, 0, stream>>>(deg, boffs, offs, N);
  // 6. gemm0 (B direct from L2, no LDS/barriers) || build_csr (atomic-free)
  mega2_kernel<<<nG + nC, 512, 0, stream>>>(x, w0p, z0b, al0, ar0, el0, er0, N,
                                            src, dst, offs, slot, ssrc, E, nG, nC);
  // 7. layer-0 aggregation + ELU -> h0b
  agg0_kernel<<<(N + 3) / 4, 256, 0, stream>>>(offs, ssrc, el0, er0, z0b, b0, h0b, N);
  // 8. layer-1 GEMM + fused el/er
  gemm1_mfma_kernel<<<(N + 63) / 64, 256, 0, stream>>>(h0b, w1p, z1b, al1, ar1, el1, er1, N);
  // 9. layer-1 aggregation -> out
  agg1_kernel<<<(N + 3) / 4, 256, 0, stream>>>(offs, ssrc, el1, er1, z1b, b1, out, N);
}

// Round 13
// 302.458 us; speedup vs baseline: 1.1489x; 1.0142x over previous
//
#include <hip/hip_runtime.h>
#include <math.h>

using bf16x8 = __attribute__((ext_vector_type(8))) short;
using f32x4  = __attribute__((ext_vector_type(4))) float;

// ---- bf16 helpers ----
__device__ __forceinline__ unsigned short f2bf(float v) {          // RNE pack
  unsigned int b = __float_as_uint(v);
  unsigned int r = (b + 0x7fffu + ((b >> 16) & 1u)) >> 16;
  return (unsigned short)r;
}
__device__ __forceinline__ float bf2f(unsigned short u) {
  return __uint_as_float(((unsigned int)u) << 16);
}

// ============================ pack: W0/W1 -> MFMA-fragment bf16 layout (38 blocks) ============================

__global__ void pack_kernel(const float* __restrict__ W0f, unsigned short* __restrict__ Bp0,
                            const float* __restrict__ W1f, unsigned short* __restrict__ Bp1) {
  int idx = blockIdx.x * 256 + threadIdx.x;
  if (idx < 8192) {
    int lane = idx & 63, s = (idx >> 6) & 7, t = idx >> 9;
    int n = t * 16 + (lane & 15), quad = lane >> 4;
    unsigned short* o = Bp0 + (size_t)idx * 8;
    #pragma unroll
    for (int j = 0; j < 8; ++j) {
      int k = s * 32 + quad * 8 + j;
      o[j] = f2bf(W0f[(size_t)k * 256 + n]);
    }
  } else if (idx < 8192 + 1536) {
    int i1 = idx - 8192;
    int lane = i1 & 63, s = (i1 >> 6) & 7, t = i1 >> 9;
    int n = t * 16 + (lane & 15), quad = lane >> 4;
    unsigned short* o = Bp1 + (size_t)i1 * 8;
    #pragma unroll
    for (int j = 0; j < 8; ++j) {
      int k = s * 32 + quad * 8 + j;
      o[j] = (n < 40) ? f2bf(W1f[(size_t)k * 40 + n]) : 0;
    }
  }
}

// ============================ 3-phase parallel scan (proven R5-R16) ============================

__global__ void block_sum_kernel(const int* __restrict__ deg, int* __restrict__ bsum, int n) {
  __shared__ int red[4];
  int t = threadIdx.x, i = blockIdx.x * 256 + t;
  int v = (i < n) ? deg[i] : 0;
  #pragma unroll
  for (int off = 32; off; off >>= 1) v += __shfl_xor(v, off);
  if ((t & 63) == 0) red[t >> 6] = v;
  __syncthreads();
  if (t == 0) bsum[blockIdx.x] = red[0] + red[1] + red[2] + red[3];
}

__global__ void scan_bsum_kernel(const int* __restrict__ bsum, int* __restrict__ boffs,
                                 int* __restrict__ offsets, int nb, int n) {
  __shared__ int tmp[1024];
  int t = threadIdx.x;
  int v = (t < nb) ? bsum[t] : 0;
  tmp[t] = v;
  __syncthreads();
  #pragma unroll
  for (int off = 1; off < 1024; off <<= 1) {
    int add = (t >= off) ? tmp[t - off] : 0;
    __syncthreads();
    tmp[t] += add;
    __syncthreads();
  }
  if (t < nb) boffs[t] = tmp[t] - v;
  if (t == 1023) offsets[n] = tmp[1023];
}

__global__ void write_offsets_kernel(const int* __restrict__ deg, const int* __restrict__ boffs,
                                     int* __restrict__ offsets, int n) {
  __shared__ int tmp[256];
  int t = threadIdx.x, i = blockIdx.x * 256 + t;
  int v = (i < n) ? deg[i] : 0;
  tmp[t] = v;
  __syncthreads();
  #pragma unroll
  for (int off = 1; off < 256; off <<= 1) {
    int add = (t >= off) ? tmp[t - off] : 0;
    __syncthreads();
    tmp[t] += add;
    __syncthreads();
  }
  if (i < n) offsets[i] = boffs[blockIdx.x] + tmp[t] - v;
}

// ============================ mega_hg: gemm0 (R12 no-LDS form) || hist+slot ============================
// gemm0 and hist are mutually independent (gemm0 needs only the pack; hist feeds the scan
// chain) -- previously they ran in SERIAL kernels. Fused: gemm0 blocks (load-latency-bound)
// and hist blocks (atomic-latency-bound) co-resident, hiding each other's stalls.

__global__ __launch_bounds__(512) void mega_hg_kernel(
    const float* __restrict__ A, const unsigned short* __restrict__ Bp,
    unsigned short* __restrict__ Zb,
    const float* __restrict__ al, const float* __restrict__ arr,
    float* __restrict__ el, float* __restrict__ er, int M,
    const int* __restrict__ dst, int* __restrict__ deg, int* __restrict__ slot,
    int E, int nG) {
  int bx = blockIdx.x;
  int tid = threadIdx.x;

  if (bx >= nG) {                                // ---- hist + slot capture ----
    int t = (bx - nG) * 512 + tid;
    if (t < E) slot[t] = atomicAdd(&deg[dst[t]], 1);
    return;
  }

  // ---- gemm0 part (exact R12: B direct from L2, no LDS, no barriers) ----
  int gx = bx >> 1, y = bx & 1;
  int wid = tid >> 6, lane = tid & 63;
  int quad = lane >> 4, col16 = lane & 15;
  int wr = wid >> 1, wc = wid & 1;               // 4 row-waves x 2 col-waves
  int rowbase = gx * 256 + wr * 64;

  // clamped row pointers (branch-free A loads; clamped rows only affect unwritten C-rows)
  const float* aptr[4];
  #pragma unroll
  for (int rt = 0; rt < 4; ++rt) {
    int m = rowbase + rt * 16 + col16;
    if (m > M - 1) m = M - 1;
    aptr[rt] = A + (size_t)m * 256 + quad * 8;
  }

  f32x4 acc[4][4];
  #pragma unroll
  for (int rt = 0; rt < 4; ++rt)
    #pragma unroll
    for (int ct = 0; ct < 4; ++ct) acc[rt][ct] = {0.f, 0.f, 0.f, 0.f};

  const bf16x8* BpV = (const bf16x8*)Bp;         // B frags straight from L1/L2-hot global

  auto loadA = [&](bf16x8* fr, int s) {
    #pragma unroll
    for (int rt = 0; rt < 4; ++rt) {
      const float* ap = aptr[rt] + s * 32;
      float4 a0 = *(const float4*)ap;
      float4 a1 = *(const float4*)(ap + 4);
      fr[rt][0] = (short)f2bf(a0.x); fr[rt][1] = (short)f2bf(a0.y);
      fr[rt][2] = (short)f2bf(a0.z); fr[rt][3] = (short)f2bf(a0.w);
      fr[rt][4] = (short)f2bf(a1.x); fr[rt][5] = (short)f2bf(a1.y);
      fr[rt][6] = (short)f2bf(a1.z); fr[rt][7] = (short)f2bf(a1.w);
    }
  };

  bf16x8 afc[4];
  loadA(afc, 0);
  for (int s = 0; s < 8; ++s) {
    bf16x8 afn[4];
    if (s < 7) loadA(afn, s + 1);                // prefetch next k-step
    #pragma unroll
    for (int ct = 0; ct < 4; ++ct) {
      bf16x8 bf = BpV[y * 4096 + ((wc * 4 + ct) * 8 + s) * 64 + lane];
      #pragma unroll
      for (int rt = 0; rt < 4; ++rt)
        acc[rt][ct] = __builtin_amdgcn_mfma_f32_16x16x32_bf16(afc[rt], bf, acc[rt][ct], 0, 0, 0);
    }
    if (s < 7) {
      #pragma unroll
      for (int rt = 0; rt < 4; ++rt) afc[rt] = afn[rt];
    }
  }

  int hw = y * 2 + wc;
  float al_c[4], ar_c[4];
  #pragma unroll
  for (int ct = 0; ct < 4; ++ct) {
    int col = y * 128 + (wc * 4 + ct) * 16 + col16;
    al_c[ct] = al[col];
    ar_c[ct] = arr[col];
  }

  #pragma unroll
  for (int rt = 0; rt < 4; ++rt) {
    int row0 = rowbase + rt * 16 + quad * 4;
    #pragma unroll
    for (int r = 0; r < 4; ++r) {
      int row = row0 + r;
      if (row < M) {
        #pragma unroll
        for (int ct = 0; ct < 4; ++ct) {
          int col = y * 128 + (wc * 4 + ct) * 16 + col16;
          Zb[(size_t)row * 256 + col] = f2bf(acc[rt][ct][r]);
        }
      }
      float pe = 0.f, pr = 0.f;
      #pragma unroll
      for (int ct = 0; ct < 4; ++ct) {
        float zv = acc[rt][ct][r];
        pe += zv * al_c[ct];
        pr += zv * ar_c[ct];
      }
      pe += __shfl_xor(pe, 1); pr += __shfl_xor(pr, 1);
      pe += __shfl_xor(pe, 2); pr += __shfl_xor(pr, 2);
      pe += __shfl_xor(pe, 4); pr += __shfl_xor(pr, 4);
      pe += __shfl_xor(pe, 8); pr += __shfl_xor(pr, 8);
      if (col16 == 0 && row < M) {
        el[(size_t)row * 4 + hw] = pe;
        er[(size_t)row * 4 + hw] = pr;
      }
    }
  }
}

// ============================ csr scatter: standalone, atomic-free ============================

__global__ __launch_bounds__(256) void csr_kernel(
    const int* __restrict__ src, const int* __restrict__ dst,
    const int* __restrict__ offs, const int* __restrict__ slot,
    int* __restrict__ ssrc, int E) {
  int e = blockIdx.x * 256 + threadIdx.x;
  if (e < E) {
    int p = offs[dst[e]] + slot[e];
    ssrc[p] = src[e];
  }
}

// ============================ layer-1 GEMM (proven R9) ============================

__global__ __launch_bounds__(256) void gemm1_mfma_kernel(
    const unsigned short* __restrict__ Ab, const unsigned short* __restrict__ Bp,
    unsigned short* __restrict__ Zb,
    const float* __restrict__ al, const float* __restrict__ arr,
    float* __restrict__ el, float* __restrict__ er, int M) {
  int wid = threadIdx.x >> 6, lane = threadIdx.x & 63;
  int quad = lane >> 4, col16 = lane & 15;
  int m = blockIdx.x * 64 + wid * 16 + col16;

  f32x4 acc[3];
  #pragma unroll
  for (int t = 0; t < 3; ++t) acc[t] = {0.f, 0.f, 0.f, 0.f};

  const bf16x8* BpV = (const bf16x8*)Bp;

  for (int s = 0; s < 8; ++s) {
    bf16x8 af;
    if (m < M) {
      af = *(const bf16x8*)(Ab + (size_t)m * 256 + s * 32 + quad * 8);
    } else {
      #pragma unroll
      for (int j = 0; j < 8; ++j) af[j] = 0;
    }
    #pragma unroll
    for (int t = 0; t < 3; ++t) {
      bf16x8 bf = BpV[(t * 8 + s) * 64 + lane];
      acc[t] = __builtin_amdgcn_mfma_f32_16x16x32_bf16(af, bf, acc[t], 0, 0, 0);
    }
  }

  float al_c[3], ar_c[3];
  #pragma unroll
  for (int t = 0; t < 3; ++t) {
    int col = t * 16 + col16;
    al_c[t] = (col < 40) ? al[col] : 0.f;
    ar_c[t] = (col < 40) ? arr[col] : 0.f;
  }

  int row0 = blockIdx.x * 64 + wid * 16 + quad * 4;
  #pragma unroll
  for (int r = 0; r < 4; ++r) {
    int row = row0 + r;
    if (row < M) {
      #pragma unroll
      for (int t = 0; t < 3; ++t) {
        int col = t * 16 + col16;
        if (col < 40) Zb[(size_t)row * 40 + col] = f2bf(acc[t][r]);
      }
    }
    float pe = 0.f, pr = 0.f;
    #pragma unroll
    for (int t = 0; t < 3; ++t) {
      pe += acc[t][r] * al_c[t];
      pr += acc[t][r] * ar_c[t];
    }
    pe += __shfl_xor(pe, 1); pr += __shfl_xor(pr, 1);
    pe += __shfl_xor(pe, 2); pr += __shfl_xor(pr, 2);
    pe += __shfl_xor(pe, 4); pr += __shfl_xor(pr, 4);
    pe += __shfl_xor(pe, 8); pr += __shfl_xor(pr, 8);
    if (col16 == 0 && row < M) {
      el[row] = pe;
      er[row] = pr;
    }
  }
}

// ============================ layer-0 aggregation (R6 form, at memory roofline) ============================

__global__ __launch_bounds__(256) void agg0_kernel(
    const int* __restrict__ offs, const int* __restrict__ ssrc,
    const float* __restrict__ el, const float* __restrict__ er,
    const unsigned short* __restrict__ zb, const float* __restrict__ bias,
    unsigned short* __restrict__ outb, int n) {
  __shared__ float sW[4][16][4];
  __shared__ int   sS[4][16];
  int wid  = threadIdx.x >> 6;
  int lane = threadIdx.x & 63;
  int node = blockIdx.x * 4 + wid;
  if (node >= n) return;
  int c = lane & 3, eoff = lane >> 2;
  int half = lane >> 5, colg = lane & 31, h2 = colg >> 3;
  int s0 = offs[node], s1 = offs[node + 1];
  float er_c = er[node * 4 + c];
  const unsigned short* zcol = zb + (colg << 3);

  float ssum = 0.f;
  float acc[8] = {0.f, 0.f, 0.f, 0.f, 0.f, 0.f, 0.f, 0.f};
  for (int base = s0; base < s1; base += 16) {
    int cnt = min(16, s1 - base);
    if (eoff < cnt) {
      int esrc = ssrc[base + eoff];
      float v = el[esrc * 4 + c] + er_c;
      v = v > 0.f ? v : 0.2f * v;              // leaky_relu(0.2)
      sW[wid][eoff][c] = expf(v);              // no max-shift (scores O(+-10))
      if (c == 0) sS[wid][eoff] = esrc;
    }
    for (int j = 0; j < cnt; j += 8) {
      float w[4];
      bf16x8 zu[4];
      #pragma unroll
      for (int u = 0; u < 4; ++u) {
        int jj = j + 2 * u + half;
        if (jj < cnt) {
          w[u] = sW[wid][jj][h2];
          int sn = sS[wid][jj];
          zu[u] = *(const bf16x8*)(zcol + (size_t)sn * 256);
        } else {
          w[u] = 0.f;
          #pragma unroll
          for (int i = 0; i < 8; ++i) zu[u][i] = 0;
        }
      }
      #pragma unroll
      for (int u = 0; u < 4; ++u) {
        ssum += w[u];
        #pragma unroll
        for (int i = 0; i < 8; ++i)
          acc[i] += w[u] * bf2f((unsigned short)zu[u][i]);
      }
    }
  }

  ssum += __shfl_xor(ssum, 32);
  #pragma unroll
  for (int i = 0; i < 8; ++i) acc[i] += __shfl_xor(acc[i], 32);

  float inv = (s1 > s0) ? 1.f / ssum : 0.f;    // deg==0 -> out = bias
  if (half == 0) {
    const float4 b0v = *(const float4*)(bias + (colg << 3));
    const float4 b1v = *(const float4*)(bias + (colg << 3) + 4);
    float bb[8] = {b0v.x, b0v.y, b0v.z, b0v.w, b1v.x, b1v.y, b1v.z, b1v.w};
    bf16x8 u;
    #pragma unroll
    for (int i = 0; i < 8; ++i) {
      float o = acc[i] * inv + bb[i];
      o = o > 0.f ? o : expm1f(o);             // ELU
      u[i] = (short)f2bf(o);
    }
    *(bf16x8*)(outb + (size_t)node * 256 + (colg << 3)) = u;
  }
}

// ============================ layer-1 aggregation (proven R12) ============================

__global__ __launch_bounds__(256) void agg1_kernel(
    const int* __restrict__ offs, const int* __restrict__ ssrc,
    const float* __restrict__ el, const float* __restrict__ er,
    const unsigned short* __restrict__ zb, const float* __restrict__ bias,
    float* __restrict__ out, int n) {
  __shared__ float sW[4][64];
  __shared__ int   sS[4][64];
  int wid  = threadIdx.x >> 6;
  int lane = threadIdx.x & 63;
  int node = blockIdx.x * 4 + wid;
  if (node >= n) return;
  int half = lane >> 5, d = lane & 31;
  int s0 = offs[node], s1 = offs[node + 1];
  float ern = er[node];

  float ssum = 0.f;
  float2 acc = make_float2(0.f, 0.f);
  for (int base = s0; base < s1; base += 64) {
    int cnt = min(64, s1 - base);
    if (lane < cnt) {
      int esrc = ssrc[base + lane];
      float v = el[esrc] + ern;
      v = v > 0.f ? v : 0.2f * v;
      sW[wid][lane] = expf(v);                 // no max-shift
      sS[wid][lane] = esrc;
    }
    for (int j = 0; j < cnt; j += 2) {
      int jj = j + half;
      float w = (jj < cnt) ? sW[wid][jj] : 0.f;
      int sn = sS[wid][(jj < cnt) ? jj : (cnt - 1)];
      ssum += w;
      if (d < 20) {
        unsigned zp = *(const unsigned*)(zb + (size_t)sn * 40 + (d << 1));
        acc.x += w * bf2f((unsigned short)(zp & 0xffffu));
        acc.y += w * bf2f((unsigned short)(zp >> 16));
      }
    }
  }

  ssum  += __shfl_xor(ssum, 32);
  acc.x += __shfl_xor(acc.x, 32);
  acc.y += __shfl_xor(acc.y, 32);

  float inv = (s1 > s0) ? 1.f / ssum : 0.f;
  if (half == 0 && d < 20) {
    float2 o;
    o.x = acc.x * inv + bias[(d << 1) + 0];
    o.y = acc.y * inv + bias[(d << 1) + 1];
    *(float2*)(out + (size_t)node * 40 + (d << 1)) = o;
  }
}

// ============================ launch ============================

extern "C" void kernel_launch(void* const* d_in, const int* in_sizes, int n_in,
                              void* d_out, int out_size, void* d_ws, size_t ws_size,
                              hipStream_t stream) {
  const float* x   = (const float*)d_in[0];
  const int*   src = (const int*)d_in[1];
  const int*   dst = (const int*)d_in[2];
  const float* W0  = (const float*)d_in[3];
  const float* al0 = (const float*)d_in[4];
  const float* ar0 = (const float*)d_in[5];
  const float* b0  = (const float*)d_in[6];
  const float* W1  = (const float*)d_in[7];
  const float* al1 = (const float*)d_in[8];
  const float* ar1 = (const float*)d_in[9];
  const float* b1  = (const float*)d_in[10];
  float* out = (float*)d_out;

  const int N = in_sizes[0] / 256;   // 50000
  const int E = in_sizes[1];         // 800000
  const int NB = (N + 255) / 256;    // 196 scan blocks

  char* ws = (char*)d_ws;
  size_t off = 0;
  auto alloc = [&](size_t bytes) {
    void* p = ws + off;
    off = (off + bytes + 255) & ~(size_t)255;
    return p;
  };
  unsigned short* z0b = (unsigned short*)alloc((size_t)N * 256 * 2);
  unsigned short* h0b = (unsigned short*)alloc((size_t)N * 256 * 2);
  unsigned short* z1b = (unsigned short*)alloc((size_t)N * 40 * 2);
  unsigned short* w0p = (unsigned short*)alloc((size_t)16 * 8 * 64 * 8 * 2);
  unsigned short* w1p = (unsigned short*)alloc((size_t)3 * 8 * 64 * 8 * 2);
  float* el0  = (float*)alloc((size_t)N * 4 * 4);
  float* er0  = (float*)alloc((size_t)N * 4 * 4);
  float* el1  = (float*)alloc((size_t)N * 4);
  float* er1  = (float*)alloc((size_t)N * 4);
  int* deg    = (int*)alloc((size_t)N * 4);
  int* offs   = (int*)alloc((size_t)(N + 1) * 4);
  int* slot   = (int*)alloc((size_t)E * 4);
  int* bsum   = (int*)alloc((size_t)NB * 4);
  int* boffs  = (int*)alloc((size_t)NB * 4);
  int* ssrc   = (int*)alloc((size_t)E * 4);
  (void)off; (void)ws_size; (void)n_in; (void)out_size;

  const int nG = ((N + 255) / 256) * 2;          // 392 gemm0 blocks (256 rows x col-half)
  const int nH512 = (E + 511) / 512;             // 1563 hist blocks (512 thr)
  const int nCSR = (E + 255) / 256;              // 3125 csr blocks

  // 1. deg = 0
  hipMemsetAsync(deg, 0, (size_t)N * 4, stream);
  // 2. pack (tiny, feeds gemm0)
  pack_kernel<<<38, 256, 0, stream>>>(W0, w0p, W1, w1p);
  // 3. gemm0 || hist+slot  (the two independent heavy phases, co-resident)
  mega_hg_kernel<<<nG + nH512, 512, 0, stream>>>(x, w0p, z0b, al0, ar0, el0, er0, N,
                                                 dst, deg, slot, E, nG);
  // 4-6. exclusive scan, 3-phase
  block_sum_kernel<<<NB, 256, 0, stream>>>(deg, bsum, N);
  scan_bsum_kernel<<<1, 1024, 0, stream>>>(bsum, boffs, offs, NB, N);
  write_offsets_kernel<<<NB, 256, 0, stream>>>(deg, boffs, offs, N);
  // 7. csr scatter (atomic-free)
  csr_kernel<<<nCSR, 256, 0, stream>>>(src, dst, offs, slot, ssrc, E);
  // 8. layer-0 aggregation + ELU -> h0b
  agg0_kernel<<<(N + 3) / 4, 256, 0, stream>>>(offs, ssrc, el0, er0, z0b, b0, h0b, N);
  // 9. layer-1 GEMM + fused el/er
  gemm1_mfma_kernel<<<(N + 63) / 64, 256, 0, stream>>>(h0b, w1p, z1b, al1, ar1, el1, er1, N);
  // 10. layer-1 aggregation -> out
  agg1_kernel<<<(N + 3) / 4, 256, 0, stream>>>(offs, ssrc, el1, er1, z1b, b1, out, N);
}